// Round 4
// baseline (284.858 us; speedup 1.0000x reference)
//
#include <hip/hip_runtime.h>

#define DIMSZ 2048
#define NH 32
#define NKV 8
#define HD 64
#define SEQLEN 2048
#define BATCH 2
#define NROWS (BATCH*SEQLEN)   // 4096
#define NQKVC 3072             // 2048 q + 512 k + 512 v

typedef __bf16 bf16x8 __attribute__((ext_vector_type(8)));
typedef float f32x4v __attribute__((ext_vector_type(4)));

__device__ __forceinline__ unsigned short f2bf(float f) {
  union { float f; unsigned int u; } v; v.f = f;
  return (unsigned short)((v.u + 0x7FFFu + ((v.u >> 16) & 1u)) >> 16);
}
__device__ __forceinline__ float bf2f(unsigned int bits16) {
  union { unsigned int u; float f; } v; v.u = bits16 << 16; return v.f;
}
// XOR swizzle for LDS tiles with 128-byte rows.
__device__ __forceinline__ int swz128(int row, int colBytes) {
  return row * 128 + (colBytes ^ ((row & 7) << 4));
}

// async global->LDS, 16B per lane. LDS dest is the wave-uniform chunk base
// (HW adds lane*16); global source is per-lane inverse-swizzled (rule #21).
#define GLOAD16(g, l) __builtin_amdgcn_global_load_lds( \
    (const __attribute__((address_space(1))) unsigned int*)(g), \
    (__attribute__((address_space(3))) unsigned int*)(l), 16, 0, 0)

// ---------------- fp32 -> bf16 convert (vectorized x4) ----------------
__global__ void k_cvt(const float* __restrict__ s, unsigned short* __restrict__ d, int n4) {
  int i = blockIdx.x * 256 + threadIdx.x;
  if (i >= n4) return;
  float4 v = reinterpret_cast<const float4*>(s)[i];
  unsigned long long pk =
      (unsigned long long)f2bf(v.x) |
      ((unsigned long long)f2bf(v.y) << 16) |
      ((unsigned long long)f2bf(v.z) << 32) |
      ((unsigned long long)f2bf(v.w) << 48);
  reinterpret_cast<unsigned long long*>(d)[i] = pk;
}

// merged wq|wk|wv convert into contiguous [3072][2048] bf16
__global__ void k_cvt_w(const float* __restrict__ wq, const float* __restrict__ wk,
                        const float* __restrict__ wv, unsigned short* __restrict__ d) {
  int i = blockIdx.x * 256 + threadIdx.x;   // 1572864 float4 total
  const float* s; int off;
  if (i < 1048576)      { s = wq; off = i; }
  else if (i < 1310720) { s = wk; off = i - 1048576; }
  else                  { s = wv; off = i - 1310720; }
  float4 v = reinterpret_cast<const float4*>(s)[off];
  unsigned long long pk =
      (unsigned long long)f2bf(v.x) |
      ((unsigned long long)f2bf(v.y) << 16) |
      ((unsigned long long)f2bf(v.z) << 32) |
      ((unsigned long long)f2bf(v.w) << 48);
  reinterpret_cast<unsigned long long*>(d)[i] = pk;
}

// ---------------- GEMM: C[M][N] = A[M][K] * B[N][K]^T ----------------
// 128x128 tile, BK=64, global_load_lds staging + XCD-aware block swizzle.
template<int OUT_BF16>
__global__ __launch_bounds__(256, 2) void k_gemm_bt(
    const unsigned short* __restrict__ A,
    const unsigned short* __restrict__ B,
    void* __restrict__ Cv, int M, int N, int K)
{
  constexpr int BK = 64;
  __shared__ __attribute__((aligned(16))) unsigned short smA[128 * BK];
  __shared__ __attribute__((aligned(16))) unsigned short smB[128 * BK];
  const int tid = threadIdx.x;
  const int lane = tid & 63;
  const int wid = tid >> 6;
  const int lr = lane & 15, lg = lane >> 4;
  // XCD swizzle (T1): nwg divisible by 8 for all our grids
  const int gx = gridDim.x;
  int lin = blockIdx.y * gx + blockIdx.x;
  const int cpx = (gx * gridDim.y) >> 3;
  lin = (lin & 7) * cpx + (lin >> 3);
  const int m0 = (lin / gx) * 128, n0 = (lin % gx) * 128;
  const int wr = (wid >> 1) * 64, wc = (wid & 1) * 64;

  f32x4v acc[4][4];
  #pragma unroll
  for (int i = 0; i < 4; i++)
    #pragma unroll
    for (int j = 0; j < 4; j++)
      acc[i][j] = f32x4v{0.f, 0.f, 0.f, 0.f};

  for (int k0 = 0; k0 < K; k0 += BK) {
    #pragma unroll
    for (int c = 0; c < 4; c++) {
      const int chunk = wid * 4 + c;
      const int idx = chunk * 64 + lane;
      const int row = idx >> 3, s = idx & 7;
      const int ks = (s ^ (row & 7)) * 8;
      GLOAD16(A + (size_t)(m0 + row) * K + k0 + ks, &smA[chunk * 512]);
      GLOAD16(B + (size_t)(n0 + row) * K + k0 + ks, &smB[chunk * 512]);
    }
    __syncthreads();
    #pragma unroll
    for (int ks = 0; ks < 2; ks++) {
      bf16x8 af[4], bfv[4];
      #pragma unroll
      for (int m = 0; m < 4; m++)
        af[m] = *reinterpret_cast<const bf16x8*>((char*)smA + swz128(wr + m * 16 + lr, ks * 64 + lg * 16));
      #pragma unroll
      for (int n = 0; n < 4; n++)
        bfv[n] = *reinterpret_cast<const bf16x8*>((char*)smB + swz128(wc + n * 16 + lr, ks * 64 + lg * 16));
      #pragma unroll
      for (int m = 0; m < 4; m++)
        #pragma unroll
        for (int n = 0; n < 4; n++)
          acc[m][n] = __builtin_amdgcn_mfma_f32_16x16x32_bf16(af[m], bfv[n], acc[m][n], 0, 0, 0);
    }
    __syncthreads();
  }
  #pragma unroll
  for (int m = 0; m < 4; m++)
    #pragma unroll
    for (int n = 0; n < 4; n++)
      #pragma unroll
      for (int r = 0; r < 4; r++) {
        const size_t row = m0 + wr + m * 16 + lg * 4 + r;  // C/D: row=(l>>4)*4+r
        const size_t col = n0 + wc + n * 16 + lr;          // col=l&15
        if (OUT_BF16) ((unsigned short*)Cv)[row * N + col] = f2bf(acc[m][n][r]);
        else          ((float*)Cv)[row * N + col] = acc[m][n][r];
      }
}

// ---------------- RoPE Q (scale 1/8 folded) ----------------
__global__ void k_rope_q(const unsigned short* __restrict__ qkv,
                         const float* __restrict__ fc, const float* __restrict__ fs,
                         unsigned short* __restrict__ Qb)
{
  const int tid = blockIdx.x * 256 + threadIdx.x;
  const int i = tid & 31;
  const int t2 = tid >> 5;
  const int h = t2 & 31;
  const int row = t2 >> 5;
  const int s = row & (SEQLEN - 1);
  const int b = row >> 11;
  const unsigned int u = *reinterpret_cast<const unsigned int*>(qkv + (size_t)row * NQKVC + h * HD + 2 * i);
  const float x0 = bf2f(u & 0xffffu), x1 = bf2f(u >> 16);
  const float c = fc[s * 32 + i], sn = fs[s * 32 + i];
  const float o0 = (x0 * c - x1 * sn) * 0.125f;
  const float o1 = (x0 * sn + x1 * c) * 0.125f;
  const unsigned int pk = (unsigned int)f2bf(o0) | ((unsigned int)f2bf(o1) << 16);
  *reinterpret_cast<unsigned int*>(Qb + ((size_t)((b * NH + h) * SEQLEN + s)) * HD + 2 * i) = pk;
}

// ---------------- RoPE K ----------------
__global__ void k_rope_k(const unsigned short* __restrict__ qkv,
                         const float* __restrict__ fc, const float* __restrict__ fs,
                         unsigned short* __restrict__ Kb)
{
  const int tid = blockIdx.x * 256 + threadIdx.x;
  const int i = tid & 31;
  const int t2 = tid >> 5;
  const int kv = t2 & 7;
  const int row = t2 >> 3;
  const int s = row & (SEQLEN - 1);
  const int b = row >> 11;
  const unsigned int u = *reinterpret_cast<const unsigned int*>(
      qkv + (size_t)row * NQKVC + DIMSZ + kv * HD + 2 * i);
  const float x0 = bf2f(u & 0xffffu), x1 = bf2f(u >> 16);
  const float c = fc[s * 32 + i], sn = fs[s * 32 + i];
  const float o0 = x0 * c - x1 * sn;
  const float o1 = x0 * sn + x1 * c;
  const unsigned int pk = (unsigned int)f2bf(o0) | ((unsigned int)f2bf(o1) << 16);
  *reinterpret_cast<unsigned int*>(Kb + ((size_t)((b * NKV + kv) * SEQLEN + s)) * HD + 2 * i) = pk;
}

// ---------------- V transpose: qkv -> Vt[b][kv][d][s] ----------------
__global__ void k_vt(const unsigned short* __restrict__ qkv, unsigned short* __restrict__ Vt) {
  __shared__ unsigned short tile[64][72];
  const int st = blockIdx.x, kv = blockIdx.y, b = blockIdx.z;
  const int tid = threadIdx.x;
  #pragma unroll
  for (int j2 = 0; j2 < 2; j2++) {
    const int s = (tid >> 3) + j2 * 32, dc = (tid & 7) * 8;
    const int row = b * SEQLEN + st * 64 + s;
    uint4 v = *reinterpret_cast<const uint4*>(
        qkv + (size_t)row * NQKVC + DIMSZ + NKV * HD + kv * HD + dc);
    const unsigned short* vs = reinterpret_cast<const unsigned short*>(&v);
    #pragma unroll
    for (int j = 0; j < 8; j++) tile[s][dc + j] = vs[j];
  }
  __syncthreads();
  {
    const int d = tid >> 2, sc = (tid & 3) * 16;
    unsigned short tmp[16];
    #pragma unroll
    for (int j = 0; j < 16; j++) tmp[j] = tile[sc + j][d];
    unsigned short* outp = Vt + ((size_t)((b * NKV + kv) * HD) + d) * SEQLEN + st * 64 + sc;
    *reinterpret_cast<uint4*>(outp)     = *reinterpret_cast<uint4*>(tmp);
    *reinterpret_cast<uint4*>(outp + 8) = *reinterpret_cast<uint4*>(tmp + 8);
  }
}

// ---------------- flash attention ----------------
// 512 threads = 8 waves x 16 q-rows; q-tile pair (qp, 15-qp) per block.
// Round 4: double-buffered K/V prefetch (1 barrier/tile), defer-max (THR=8),
// XCD swizzle so the 4 heads sharing a KV panel land on one XCD.
__global__ __launch_bounds__(512, 2) void k_attn(
    const unsigned short* __restrict__ Qg,   // [B][NH][S][HD], pre-scaled 1/8
    const unsigned short* __restrict__ Kg,   // [B][NKV][S][HD]
    const unsigned short* __restrict__ Vt,   // [B][NKV][HD][S]
    unsigned short* __restrict__ Og)         // [B*S][NH*HD]
{
  constexpr int KVB = 64;
  __shared__ __attribute__((aligned(16))) unsigned short sK[2][KVB * HD];
  __shared__ __attribute__((aligned(16))) unsigned short sV[2][HD * KVB];
  __shared__ __attribute__((aligned(16))) unsigned short sP[8 * 16 * KVB];
  const int tid = threadIdx.x;
  const int lane = tid & 63, wid = tid >> 6;
  const int lr = lane & 15, lg = lane >> 4;
  // XCD swizzle: nwg=512; contiguous chunk of 64 ids per XCD (8 q-pairs x 8 heads)
  int lin = blockIdx.z * 256 + blockIdx.y * 8 + blockIdx.x;
  lin = (lin & 7) * 64 + (lin >> 3);
  const int qp = lin & 7, h = (lin >> 3) & 31, b = lin >> 8;
  const int kvh = h >> 2;
  const unsigned short* Qp = Qg + ((size_t)(b * NH + h) * SEQLEN) * HD;
  const unsigned short* Kp = Kg + ((size_t)(b * NKV + kvh) * SEQLEN) * HD;
  const unsigned short* Vp = Vt + ((size_t)(b * NKV + kvh) * HD) * SEQLEN;
  unsigned short* Pw = sP + wid * (16 * KVB);

  // staging geometry: wave wid owns 1KB chunk wid of each 8KB tile
  const int sidx = wid * 64 + lane;
  const int srow = sidx >> 3;
  const int scol = ((sidx & 7) ^ (srow & 7)) * 8;

  for (int phase = 0; phase < 2; phase++) {
    const int qt = phase ? (15 - qp) : qp;
    const int qrow0 = qt * 128 + wid * 16;
    bf16x8 aq[2];
    #pragma unroll
    for (int ks = 0; ks < 2; ks++)
      aq[ks] = *reinterpret_cast<const bf16x8*>(Qp + (size_t)(qrow0 + lr) * HD + ks * 32 + lg * 8);

    f32x4v accO[4];
    float mrun[4], lrun[4];
    #pragma unroll
    for (int r = 0; r < 4; r++) {
      accO[r] = f32x4v{0.f, 0.f, 0.f, 0.f};
      mrun[r] = -3.0e38f; lrun[r] = 0.f;
    }

    const int nt = qt * 2 + 2;
    // prologue: stage tile 0 into buffer 0
    GLOAD16(Kp + (size_t)srow * HD + scol, &sK[0][wid * 512]);
    GLOAD16(Vp + (size_t)srow * SEQLEN + scol, &sV[0][wid * 512]);
    __syncthreads();
    int bb = 0;
    for (int t = 0; t < nt; t++) {
      const int kv0 = t * KVB;
      if (t + 1 < nt) {   // prefetch next tile into the other buffer
        const int kn = kv0 + KVB;
        GLOAD16(Kp + (size_t)(kn + srow) * HD + scol, &sK[bb ^ 1][wid * 512]);
        GLOAD16(Vp + (size_t)srow * SEQLEN + kn + scol, &sV[bb ^ 1][wid * 512]);
      }
      if (kv0 <= qrow0 + 15) {
        f32x4v sfr[4];
        #pragma unroll
        for (int c = 0; c < 4; c++) sfr[c] = f32x4v{0.f, 0.f, 0.f, 0.f};
        __builtin_amdgcn_s_setprio(1);
        #pragma unroll
        for (int ks = 0; ks < 2; ks++) {
          bf16x8 bk[4];
          #pragma unroll
          for (int c = 0; c < 4; c++)
            bk[c] = *reinterpret_cast<const bf16x8*>((char*)sK[bb] + swz128(c * 16 + lr, ks * 64 + lg * 16));
          #pragma unroll
          for (int c = 0; c < 4; c++)
            sfr[c] = __builtin_amdgcn_mfma_f32_16x16x32_bf16(aq[ks], bk[c], sfr[c], 0, 0, 0);
        }
        __builtin_amdgcn_s_setprio(0);
        if (kv0 + KVB - 1 > qrow0) {
          #pragma unroll
          for (int c = 0; c < 4; c++)
            #pragma unroll
            for (int r = 0; r < 4; r++) {
              const int q = qrow0 + lg * 4 + r;
              const int kv = kv0 + c * 16 + lr;
              if (kv > q) sfr[c][r] = -1.0e30f;
            }
        }
        #pragma unroll
        for (int r = 0; r < 4; r++) {
          float tm = fmaxf(fmaxf(sfr[0][r], sfr[1][r]), fmaxf(sfr[2][r], sfr[3][r]));
          tm = fmaxf(tm, __shfl_xor(tm, 1));
          tm = fmaxf(tm, __shfl_xor(tm, 2));
          tm = fmaxf(tm, __shfl_xor(tm, 4));
          tm = fmaxf(tm, __shfl_xor(tm, 8));
          const float mo = mrun[r];
          const bool defer = __all(tm <= mo + 8.0f);   // wave-uniform (T13)
          float mn, sc;
          if (defer) { mn = mo; }
          else { mn = fmaxf(mo, tm); sc = __expf(mo - mn); mrun[r] = mn; }
          float rs = 0.f;
          #pragma unroll
          for (int c = 0; c < 4; c++) {
            const float p = __expf(sfr[c][r] - mn);
            sfr[c][r] = p;
            rs += p;
          }
          rs += __shfl_xor(rs, 1);
          rs += __shfl_xor(rs, 2);
          rs += __shfl_xor(rs, 4);
          rs += __shfl_xor(rs, 8);
          if (defer) {
            lrun[r] += rs;
          } else {
            lrun[r] = lrun[r] * sc + rs;
            #pragma unroll
            for (int dc = 0; dc < 4; dc++) accO[dc][r] *= sc;
          }
        }
        // P -> per-wave LDS (C-layout scatter), re-read in A-layout
        #pragma unroll
        for (int c = 0; c < 4; c++)
          #pragma unroll
          for (int r = 0; r < 4; r++)
            *reinterpret_cast<unsigned short*>(
                (char*)Pw + swz128(lg * 4 + r, (c * 16 + lr) * 2)) = f2bf(sfr[c][r]);
        __builtin_amdgcn_s_setprio(1);
        #pragma unroll
        for (int ks = 0; ks < 2; ks++) {
          bf16x8 ap = *reinterpret_cast<const bf16x8*>((char*)Pw + swz128(lr, ks * 64 + lg * 16));
          bf16x8 bv[4];
          #pragma unroll
          for (int dc = 0; dc < 4; dc++)
            bv[dc] = *reinterpret_cast<const bf16x8*>((char*)sV[bb] + swz128(dc * 16 + lr, ks * 64 + lg * 16));
          #pragma unroll
          for (int dc = 0; dc < 4; dc++)
            accO[dc] = __builtin_amdgcn_mfma_f32_16x16x32_bf16(ap, bv[dc], accO[dc], 0, 0, 0);
        }
        __builtin_amdgcn_s_setprio(0);
      }
      __syncthreads();   // drains prefetch vmcnt + protects buffers
      bb ^= 1;
    }
    // normalize + store
    #pragma unroll
    for (int r = 0; r < 4; r++) {
      const float inv = 1.0f / lrun[r];
      const int q = qrow0 + lg * 4 + r;
      #pragma unroll
      for (int dc = 0; dc < 4; dc++) {
        const int d = dc * 16 + lr;
        Og[(size_t)(b * SEQLEN + q) * DIMSZ + h * HD + d] = f2bf(accO[dc][r] * inv);
      }
    }
  }
}

extern "C" void kernel_launch(void* const* d_in, const int* in_sizes, int n_in,
                              void* d_out, int out_size, void* d_ws, size_t ws_size,
                              hipStream_t stream)
{
  const float* x  = (const float*)d_in[0];
  const float* fc = (const float*)d_in[1];
  const float* fs = (const float*)d_in[2];
  const float* wq = (const float*)d_in[3];
  const float* wk = (const float*)d_in[4];
  const float* wv = (const float*)d_in[5];
  const float* wo = (const float*)d_in[6];
  float* out = (float*)d_out;
  char* ws = (char*)d_ws;

  unsigned short* xb    = (unsigned short*)(ws + 0);          // [4096][2048]
  unsigned short* wqkvb = (unsigned short*)(ws + 16777216);   // [3072][2048]
  unsigned short* wob   = (unsigned short*)(ws + 29360128);   // [2048][2048]
  unsigned short* qkv   = (unsigned short*)(ws + 37748736);   // [4096][3072]
  unsigned short* Qb    = (unsigned short*)(ws + 62914560);   // [2][32][2048][64]
  unsigned short* Kb    = (unsigned short*)(ws + 79691776);   // [2][8][2048][64]
  unsigned short* Vtb   = (unsigned short*)(ws + 83886080);   // [2][8][64][2048]
  unsigned short* attnb = (unsigned short*)(ws + 88080384);   // [4096][2048]

  k_cvt<<<8192, 256, 0, stream>>>(x,  xb, 2097152);
  k_cvt_w<<<6144, 256, 0, stream>>>(wq, wk, wv, wqkvb);
  k_cvt<<<4096, 256, 0, stream>>>(wo, wob, 1048576);

  dim3 g1(24, 32);   // N=3072/128, M=4096/128
  k_gemm_bt<1><<<g1, 256, 0, stream>>>(xb, wqkvb, qkv, NROWS, NQKVC, DIMSZ);

  k_rope_q<<<16384, 256, 0, stream>>>(qkv, fc, fs, Qb);
  k_rope_k<<<4096, 256, 0, stream>>>(qkv, fc, fs, Kb);
  dim3 gv(32, 8, 2);
  k_vt<<<gv, 256, 0, stream>>>(qkv, Vtb);

  dim3 ga(8, 32, 2);   // q-tile pairs, heads, batch
  k_attn<<<ga, 512, 0, stream>>>(Qb, Kb, Vtb, attnb);

  dim3 g2(16, 32);     // N=2048/128, M=4096/128
  k_gemm_bt<0><<<g2, 256, 0, stream>>>(attnb, wob, out, NROWS, DIMSZ, DIMSZ);
}

// Round 5
// 196.730 us; speedup vs baseline: 1.4480x; 1.4480x over previous
//
#include <hip/hip_runtime.h>

#define DIMSZ 2048
#define NH 32
#define NKV 8
#define HD 64
#define SEQLEN 2048
#define BATCH 2
#define NROWS (BATCH*SEQLEN)   // 4096
#define NQKVC 3072             // 2048 q + 512 k + 512 v

typedef __bf16 bf16x8 __attribute__((ext_vector_type(8)));
typedef float f32x4v __attribute__((ext_vector_type(4)));

__device__ __forceinline__ unsigned short f2bf(float f) {
  union { float f; unsigned int u; } v; v.f = f;
  return (unsigned short)((v.u + 0x7FFFu + ((v.u >> 16) & 1u)) >> 16);
}
__device__ __forceinline__ float bf2f(unsigned int bits16) {
  union { unsigned int u; float f; } v; v.u = bits16 << 16; return v.f;
}
// XOR swizzle for LDS tiles with 128-byte rows.
__device__ __forceinline__ int swz128(int row, int colBytes) {
  return row * 128 + (colBytes ^ ((row & 7) << 4));
}

// async global->LDS, 16B per lane. LDS dest is the wave-uniform chunk base
// (HW adds lane*16); global source is per-lane inverse-swizzled (rule #21).
#define GLOAD16(g, l) __builtin_amdgcn_global_load_lds( \
    (const __attribute__((address_space(1))) unsigned int*)(g), \
    (__attribute__((address_space(3))) unsigned int*)(l), 16, 0, 0)

// ---------------- fp32 -> bf16 convert (vectorized x4) ----------------
__global__ void k_cvt(const float* __restrict__ s, unsigned short* __restrict__ d, int n4) {
  int i = blockIdx.x * 256 + threadIdx.x;
  if (i >= n4) return;
  float4 v = reinterpret_cast<const float4*>(s)[i];
  unsigned long long pk =
      (unsigned long long)f2bf(v.x) |
      ((unsigned long long)f2bf(v.y) << 16) |
      ((unsigned long long)f2bf(v.z) << 32) |
      ((unsigned long long)f2bf(v.w) << 48);
  reinterpret_cast<unsigned long long*>(d)[i] = pk;
}

// merged wq|wk|wv convert into contiguous [3072][2048] bf16
__global__ void k_cvt_w(const float* __restrict__ wq, const float* __restrict__ wk,
                        const float* __restrict__ wv, unsigned short* __restrict__ d) {
  int i = blockIdx.x * 256 + threadIdx.x;   // 1572864 float4 total
  const float* s; int off;
  if (i < 1048576)      { s = wq; off = i; }
  else if (i < 1310720) { s = wk; off = i - 1048576; }
  else                  { s = wv; off = i - 1310720; }
  float4 v = reinterpret_cast<const float4*>(s)[off];
  unsigned long long pk =
      (unsigned long long)f2bf(v.x) |
      ((unsigned long long)f2bf(v.y) << 16) |
      ((unsigned long long)f2bf(v.z) << 32) |
      ((unsigned long long)f2bf(v.w) << 48);
  reinterpret_cast<unsigned long long*>(d)[i] = pk;
}

// ---------------- GEMM: C[M][N] = A[M][K] * B[N][K]^T ----------------
// 128x128 tile, BK=64, global_load_lds staging + XCD-aware block swizzle.
template<int OUT_BF16>
__global__ __launch_bounds__(256, 2) void k_gemm_bt(
    const unsigned short* __restrict__ A,
    const unsigned short* __restrict__ B,
    void* __restrict__ Cv, int M, int N, int K)
{
  constexpr int BK = 64;
  __shared__ __attribute__((aligned(16))) unsigned short smA[128 * BK];
  __shared__ __attribute__((aligned(16))) unsigned short smB[128 * BK];
  const int tid = threadIdx.x;
  const int lane = tid & 63;
  const int wid = tid >> 6;
  const int lr = lane & 15, lg = lane >> 4;
  // XCD swizzle (T1): nwg divisible by 8 for all our grids
  const int gx = gridDim.x;
  int lin = blockIdx.y * gx + blockIdx.x;
  const int cpx = (gx * gridDim.y) >> 3;
  lin = (lin & 7) * cpx + (lin >> 3);
  const int m0 = (lin / gx) * 128, n0 = (lin % gx) * 128;
  const int wr = (wid >> 1) * 64, wc = (wid & 1) * 64;

  f32x4v acc[4][4];
  #pragma unroll
  for (int i = 0; i < 4; i++)
    #pragma unroll
    for (int j = 0; j < 4; j++)
      acc[i][j] = f32x4v{0.f, 0.f, 0.f, 0.f};

  for (int k0 = 0; k0 < K; k0 += BK) {
    #pragma unroll
    for (int c = 0; c < 4; c++) {
      const int chunk = wid * 4 + c;
      const int idx = chunk * 64 + lane;
      const int row = idx >> 3, s = idx & 7;
      const int ks = (s ^ (row & 7)) * 8;
      GLOAD16(A + (size_t)(m0 + row) * K + k0 + ks, &smA[chunk * 512]);
      GLOAD16(B + (size_t)(n0 + row) * K + k0 + ks, &smB[chunk * 512]);
    }
    __syncthreads();
    #pragma unroll
    for (int ks = 0; ks < 2; ks++) {
      bf16x8 af[4], bfv[4];
      #pragma unroll
      for (int m = 0; m < 4; m++)
        af[m] = *reinterpret_cast<const bf16x8*>((char*)smA + swz128(wr + m * 16 + lr, ks * 64 + lg * 16));
      #pragma unroll
      for (int n = 0; n < 4; n++)
        bfv[n] = *reinterpret_cast<const bf16x8*>((char*)smB + swz128(wc + n * 16 + lr, ks * 64 + lg * 16));
      #pragma unroll
      for (int m = 0; m < 4; m++)
        #pragma unroll
        for (int n = 0; n < 4; n++)
          acc[m][n] = __builtin_amdgcn_mfma_f32_16x16x32_bf16(af[m], bfv[n], acc[m][n], 0, 0, 0);
    }
    __syncthreads();
  }
  #pragma unroll
  for (int m = 0; m < 4; m++)
    #pragma unroll
    for (int n = 0; n < 4; n++)
      #pragma unroll
      for (int r = 0; r < 4; r++) {
        const size_t row = m0 + wr + m * 16 + lg * 4 + r;  // C/D: row=(l>>4)*4+r
        const size_t col = n0 + wc + n * 16 + lr;          // col=l&15
        if (OUT_BF16) ((unsigned short*)Cv)[row * N + col] = f2bf(acc[m][n][r]);
        else          ((float*)Cv)[row * N + col] = acc[m][n][r];
      }
}

// ---------------- RoPE Q (scale 1/8 * log2(e) folded: QK^T lands in log2 domain) ----------------
__global__ void k_rope_q(const unsigned short* __restrict__ qkv,
                         const float* __restrict__ fc, const float* __restrict__ fs,
                         unsigned short* __restrict__ Qb)
{
  const int tid = blockIdx.x * 256 + threadIdx.x;
  const int i = tid & 31;
  const int t2 = tid >> 5;
  const int h = t2 & 31;
  const int row = t2 >> 5;
  const int s = row & (SEQLEN - 1);
  const int b = row >> 11;
  const unsigned int u = *reinterpret_cast<const unsigned int*>(qkv + (size_t)row * NQKVC + h * HD + 2 * i);
  const float x0 = bf2f(u & 0xffffu), x1 = bf2f(u >> 16);
  const float c = fc[s * 32 + i], sn = fs[s * 32 + i];
  const float SCL = 0.18033688011112043f;   // 0.125 * log2(e)
  const float o0 = (x0 * c - x1 * sn) * SCL;
  const float o1 = (x0 * sn + x1 * c) * SCL;
  const unsigned int pk = (unsigned int)f2bf(o0) | ((unsigned int)f2bf(o1) << 16);
  *reinterpret_cast<unsigned int*>(Qb + ((size_t)((b * NH + h) * SEQLEN + s)) * HD + 2 * i) = pk;
}

// ---------------- RoPE K ----------------
__global__ void k_rope_k(const unsigned short* __restrict__ qkv,
                         const float* __restrict__ fc, const float* __restrict__ fs,
                         unsigned short* __restrict__ Kb)
{
  const int tid = blockIdx.x * 256 + threadIdx.x;
  const int i = tid & 31;
  const int t2 = tid >> 5;
  const int kv = t2 & 7;
  const int row = t2 >> 3;
  const int s = row & (SEQLEN - 1);
  const int b = row >> 11;
  const unsigned int u = *reinterpret_cast<const unsigned int*>(
      qkv + (size_t)row * NQKVC + DIMSZ + kv * HD + 2 * i);
  const float x0 = bf2f(u & 0xffffu), x1 = bf2f(u >> 16);
  const float c = fc[s * 32 + i], sn = fs[s * 32 + i];
  const float o0 = x0 * c - x1 * sn;
  const float o1 = x0 * sn + x1 * c;
  const unsigned int pk = (unsigned int)f2bf(o0) | ((unsigned int)f2bf(o1) << 16);
  *reinterpret_cast<unsigned int*>(Kb + ((size_t)((b * NKV + kv) * SEQLEN + s)) * HD + 2 * i) = pk;
}

// ---------------- V transpose: qkv -> Vt[b][kv][d][s] ----------------
__global__ void k_vt(const unsigned short* __restrict__ qkv, unsigned short* __restrict__ Vt) {
  __shared__ unsigned short tile[64][72];
  const int st = blockIdx.x, kv = blockIdx.y, b = blockIdx.z;
  const int tid = threadIdx.x;
  #pragma unroll
  for (int j2 = 0; j2 < 2; j2++) {
    const int s = (tid >> 3) + j2 * 32, dc = (tid & 7) * 8;
    const int row = b * SEQLEN + st * 64 + s;
    uint4 v = *reinterpret_cast<const uint4*>(
        qkv + (size_t)row * NQKVC + DIMSZ + NKV * HD + kv * HD + dc);
    const unsigned short* vs = reinterpret_cast<const unsigned short*>(&v);
    #pragma unroll
    for (int j = 0; j < 8; j++) tile[s][dc + j] = vs[j];
  }
  __syncthreads();
  {
    const int d = tid >> 2, sc = (tid & 3) * 16;
    unsigned short tmp[16];
    #pragma unroll
    for (int j = 0; j < 16; j++) tmp[j] = tile[sc + j][d];
    unsigned short* outp = Vt + ((size_t)((b * NKV + kv) * HD) + d) * SEQLEN + st * 64 + sc;
    *reinterpret_cast<uint4*>(outp)     = *reinterpret_cast<uint4*>(tmp);
    *reinterpret_cast<uint4*>(outp + 8) = *reinterpret_cast<uint4*>(tmp + 8);
  }
}

// ---------------- flash attention ----------------
// 512 threads = 8 waves x 16 q-rows; q-tile pair (qp, 15-qp); serial staging
// (round-3 structure). Swapped QK^T: S^T = mfma(K,Q) so each lane owns one
// q-row's 16 scores in registers -> in-register softmax (2 shfls/tile).
// XCD swizzle: each XCD owns one kv-head panel (both batches) ~3MB < 4MB L2.
__global__ __launch_bounds__(512, 2) void k_attn(
    const unsigned short* __restrict__ Qg,   // [B][NH][S][HD], scaled 0.125*log2e
    const unsigned short* __restrict__ Kg,   // [B][NKV][S][HD]
    const unsigned short* __restrict__ Vt,   // [B][NKV][HD][S]
    unsigned short* __restrict__ Og)         // [B*S][NH*HD]
{
  constexpr int KVB = 64;
  __shared__ __attribute__((aligned(16))) unsigned short sK[KVB * HD];      // 8KB
  __shared__ __attribute__((aligned(16))) unsigned short sV[HD * KVB];      // 8KB
  __shared__ __attribute__((aligned(16))) unsigned short sP[8 * 16 * KVB];  // 16KB
  const int tid = threadIdx.x;
  const int lane = tid & 63, wid = tid >> 6;
  const int lr = lane & 15, lg = lane >> 4;
  // XCD swizzle: hw id -> contiguous 64-block chunk per XCD = one kvh panel
  const int orig = blockIdx.x;                   // 512 blocks, 1-D
  const int w = (orig & 7) * 64 + (orig >> 3);
  const int kvh = w >> 6;
  const int b = (w >> 5) & 1;
  const int h = kvh * 4 + ((w >> 3) & 3);
  const int qp = w & 7;
  const unsigned short* Qp = Qg + ((size_t)(b * NH + h) * SEQLEN) * HD;
  const unsigned short* Kp = Kg + ((size_t)(b * NKV + kvh) * SEQLEN) * HD;
  const unsigned short* Vp = Vt + ((size_t)(b * NKV + kvh) * HD) * SEQLEN;
  unsigned short* Pw = sP + wid * (16 * KVB);

  // staging geometry: wave wid owns 1KB chunk wid of each 8KB tile
  const int sidx = wid * 64 + lane;
  const int srow = sidx >> 3;
  const int scol = ((sidx & 7) ^ (srow & 7)) * 8;

  for (int phase = 0; phase < 2; phase++) {
    const int qt = phase ? (15 - qp) : qp;
    const int qrow0 = qt * 128 + wid * 16;
    bf16x8 aq[2];
    #pragma unroll
    for (int ks = 0; ks < 2; ks++)
      aq[ks] = *reinterpret_cast<const bf16x8*>(Qp + (size_t)(qrow0 + lr) * HD + ks * 32 + lg * 8);

    f32x4v accO[4];
    #pragma unroll
    for (int r = 0; r < 4; r++) accO[r] = f32x4v{0.f, 0.f, 0.f, 0.f};
    float mrun = -3.0e38f, lrun = 0.f;   // softmax state for q = qrow0 + lr (log2 domain)

    const int nt = qt * 2 + 2;
    for (int t = 0; t < nt; t++) {
      const int kv0 = t * KVB;
      GLOAD16(Kp + (size_t)(kv0 + srow) * HD + scol, &sK[wid * 512]);
      GLOAD16(Vp + (size_t)srow * SEQLEN + kv0 + scol, &sV[wid * 512]);
      __syncthreads();
      if (kv0 <= qrow0 + 15) {
        // S^T = K Q^T : D[row=kv][col=q]; lane owns q=qrow0+lr, kv in 16 regs
        f32x4v sfr[4];
        #pragma unroll
        for (int c = 0; c < 4; c++) sfr[c] = f32x4v{0.f, 0.f, 0.f, 0.f};
        __builtin_amdgcn_s_setprio(1);
        #pragma unroll
        for (int ks = 0; ks < 2; ks++) {
          bf16x8 bk[4];
          #pragma unroll
          for (int c = 0; c < 4; c++)
            bk[c] = *reinterpret_cast<const bf16x8*>((char*)sK + swz128(c * 16 + lr, ks * 64 + lg * 16));
          #pragma unroll
          for (int c = 0; c < 4; c++)
            sfr[c] = __builtin_amdgcn_mfma_f32_16x16x32_bf16(bk[c], aq[ks], sfr[c], 0, 0, 0);
        }
        __builtin_amdgcn_s_setprio(0);
        // causal mask: kv = kv0 + c*16 + lg*4 + r, q = qrow0 + lr
        if (kv0 + KVB - 1 > qrow0) {
          const int q = qrow0 + lr;
          #pragma unroll
          for (int c = 0; c < 4; c++)
            #pragma unroll
            for (int r = 0; r < 4; r++) {
              const int kv = kv0 + c * 16 + lg * 4 + r;
              if (kv > q) sfr[c][r] = -1.0e30f;
            }
        }
        // in-register max tree (15 ops) + 2 shfls across lg groups
        float mc[4];
        #pragma unroll
        for (int c = 0; c < 4; c++)
          mc[c] = fmaxf(fmaxf(sfr[c][0], sfr[c][1]), fmaxf(sfr[c][2], sfr[c][3]));
        float tm = fmaxf(fmaxf(mc[0], mc[1]), fmaxf(mc[2], mc[3]));
        tm = fmaxf(tm, __shfl_xor(tm, 16));
        tm = fmaxf(tm, __shfl_xor(tm, 32));
        const float mo = mrun;
        const bool defer = __all(tm <= mo + 8.0f);    // T13, log2 domain (2^8 bound)
        const float mn = defer ? mo : fmaxf(mo, tm);
        // exp2 + in-register sum tree + 2 shfls
        float rc[4];
        #pragma unroll
        for (int c = 0; c < 4; c++) {
          float p0 = __builtin_amdgcn_exp2f(sfr[c][0] - mn);
          float p1 = __builtin_amdgcn_exp2f(sfr[c][1] - mn);
          float p2 = __builtin_amdgcn_exp2f(sfr[c][2] - mn);
          float p3 = __builtin_amdgcn_exp2f(sfr[c][3] - mn);
          sfr[c][0] = p0; sfr[c][1] = p1; sfr[c][2] = p2; sfr[c][3] = p3;
          rc[c] = (p0 + p1) + (p2 + p3);
        }
        float rs = (rc[0] + rc[1]) + (rc[2] + rc[3]);
        rs += __shfl_xor(rs, 16);
        rs += __shfl_xor(rs, 32);
        if (defer) {
          lrun += rs;
        } else {
          const float sc = __builtin_amdgcn_exp2f(mo - mn);
          mrun = mn;
          lrun = lrun * sc + rs;
          // redistribute sc (lane-domain q=lr) to row-domain q=lg*4+r
          #pragma unroll
          for (int r = 0; r < 4; r++) {
            const float scr = __shfl(sc, (lg << 4) + (lg << 2) + r);
            #pragma unroll
            for (int dc = 0; dc < 4; dc++) accO[dc][r] *= scr;
          }
        }
        // P store: lane holds P[q=lr][kv=c*16+lg*4+r] -> 4x packed b64 writes
        #pragma unroll
        for (int c = 0; c < 4; c++) {
          uint2 pk;
          pk.x = (unsigned int)f2bf(sfr[c][0]) | ((unsigned int)f2bf(sfr[c][1]) << 16);
          pk.y = (unsigned int)f2bf(sfr[c][2]) | ((unsigned int)f2bf(sfr[c][3]) << 16);
          *reinterpret_cast<uint2*>((char*)Pw + swz128(lr, c * 32 + lg * 8)) = pk;
        }
        // O += P V
        __builtin_amdgcn_s_setprio(1);
        #pragma unroll
        for (int ks = 0; ks < 2; ks++) {
          bf16x8 ap = *reinterpret_cast<const bf16x8*>((char*)Pw + swz128(lr, ks * 64 + lg * 16));
          bf16x8 bv[4];
          #pragma unroll
          for (int dc = 0; dc < 4; dc++)
            bv[dc] = *reinterpret_cast<const bf16x8*>((char*)sV + swz128(dc * 16 + lr, ks * 64 + lg * 16));
          #pragma unroll
          for (int dc = 0; dc < 4; dc++)
            accO[dc] = __builtin_amdgcn_mfma_f32_16x16x32_bf16(ap, bv[dc], accO[dc], 0, 0, 0);
        }
        __builtin_amdgcn_s_setprio(0);
      }
      __syncthreads();
    }
    // normalize + store (lrun lives at lane q=lr -> shfl to row-domain)
    const float inv = 1.0f / lrun;
    #pragma unroll
    for (int r = 0; r < 4; r++) {
      const float invr = __shfl(inv, (lg << 4) + (lg << 2) + r);
      const int q = qrow0 + lg * 4 + r;
      #pragma unroll
      for (int dc = 0; dc < 4; dc++) {
        const int d = dc * 16 + lr;
        Og[(size_t)(b * SEQLEN + q) * DIMSZ + h * HD + d] = f2bf(accO[dc][r] * invr);
      }
    }
  }
}

extern "C" void kernel_launch(void* const* d_in, const int* in_sizes, int n_in,
                              void* d_out, int out_size, void* d_ws, size_t ws_size,
                              hipStream_t stream)
{
  const float* x  = (const float*)d_in[0];
  const float* fc = (const float*)d_in[1];
  const float* fs = (const float*)d_in[2];
  const float* wq = (const float*)d_in[3];
  const float* wk = (const float*)d_in[4];
  const float* wv = (const float*)d_in[5];
  const float* wo = (const float*)d_in[6];
  float* out = (float*)d_out;
  char* ws = (char*)d_ws;

  unsigned short* xb    = (unsigned short*)(ws + 0);          // [4096][2048]
  unsigned short* wqkvb = (unsigned short*)(ws + 16777216);   // [3072][2048]
  unsigned short* wob   = (unsigned short*)(ws + 29360128);   // [2048][2048]
  unsigned short* qkv   = (unsigned short*)(ws + 37748736);   // [4096][3072]
  unsigned short* Qb    = (unsigned short*)(ws + 62914560);   // [2][32][2048][64]
  unsigned short* Kb    = (unsigned short*)(ws + 79691776);   // [2][8][2048][64]
  unsigned short* Vtb   = (unsigned short*)(ws + 83886080);   // [2][8][64][2048]
  unsigned short* attnb = (unsigned short*)(ws + 88080384);   // [4096][2048]

  k_cvt<<<8192, 256, 0, stream>>>(x,  xb, 2097152);
  k_cvt_w<<<6144, 256, 0, stream>>>(wq, wk, wv, wqkvb);
  k_cvt<<<4096, 256, 0, stream>>>(wo, wob, 1048576);

  dim3 g1(24, 32);   // N=3072/128, M=4096/128
  k_gemm_bt<1><<<g1, 256, 0, stream>>>(xb, wqkvb, qkv, NROWS, NQKVC, DIMSZ);

  k_rope_q<<<16384, 256, 0, stream>>>(qkv, fc, fs, Qb);
  k_rope_k<<<4096, 256, 0, stream>>>(qkv, fc, fs, Kb);
  dim3 gv(32, 8, 2);
  k_vt<<<gv, 256, 0, stream>>>(qkv, Vtb);

  k_attn<<<512, 512, 0, stream>>>(Qb, Kb, Vtb, attnb);

  dim3 g2(16, 32);     // N=2048/128, M=4096/128
  k_gemm_bt<0><<<g2, 256, 0, stream>>>(attnb, wob, out, NROWS, DIMSZ, DIMSZ);
}

// Round 6
// 186.535 us; speedup vs baseline: 1.5271x; 1.0547x over previous
//
#include <hip/hip_runtime.h>

#define DIMSZ 2048
#define NH 32
#define NKV 8
#define HD 64
#define SEQLEN 2048
#define BATCH 2
#define NROWS (BATCH*SEQLEN)   // 4096
#define NQKVC 3072             // 2048 q + 512 k + 512 v

typedef __bf16 bf16x8 __attribute__((ext_vector_type(8)));
typedef __bf16 bf16x2 __attribute__((ext_vector_type(2)));
typedef float f32x4v __attribute__((ext_vector_type(4)));
typedef float f32x2v __attribute__((ext_vector_type(2)));

// scalar f32->bf16 (RTNE) via compiler cast — lowers to v_cvt_pk_bf16_f32 (m240)
__device__ __forceinline__ unsigned short f2bf(float f) {
  __bf16 h = (__bf16)f;
  union { __bf16 h; unsigned short u; } v; v.h = h; return v.u;
}
// packed pair convert: one v_cvt_pk_bf16_f32
__device__ __forceinline__ unsigned int pk2bf(float lo, float hi) {
  f32x2v v; v[0] = lo; v[1] = hi;
  bf16x2 h = __builtin_convertvector(v, bf16x2);
  union { bf16x2 h; unsigned int u; } c; c.h = h; return c.u;
}
__device__ __forceinline__ float bf2f(unsigned int bits16) {
  union { unsigned int u; float f; } v; v.u = bits16 << 16; return v.f;
}
// XOR swizzle for LDS tiles with 128-byte rows.
__device__ __forceinline__ int swz128(int row, int colBytes) {
  return row * 128 + (colBytes ^ ((row & 7) << 4));
}

// async global->LDS, 16B per lane. LDS dest is the wave-uniform chunk base
// (HW adds lane*16); global source is per-lane inverse-swizzled (rule #21).
#define GLOAD16(g, l) __builtin_amdgcn_global_load_lds( \
    (const __attribute__((address_space(1))) unsigned int*)(g), \
    (__attribute__((address_space(3))) unsigned int*)(l), 16, 0, 0)

// ---------------- fp32 -> bf16 convert (vectorized x4) ----------------
__global__ void k_cvt(const float* __restrict__ s, unsigned short* __restrict__ d, int n4) {
  int i = blockIdx.x * 256 + threadIdx.x;
  if (i >= n4) return;
  float4 v = reinterpret_cast<const float4*>(s)[i];
  uint2 pk; pk.x = pk2bf(v.x, v.y); pk.y = pk2bf(v.z, v.w);
  reinterpret_cast<uint2*>(d)[i] = pk;
}

// merged wq|wk|wv convert into contiguous [3072][2048] bf16
__global__ void k_cvt_w(const float* __restrict__ wq, const float* __restrict__ wk,
                        const float* __restrict__ wv, unsigned short* __restrict__ d) {
  int i = blockIdx.x * 256 + threadIdx.x;   // 1572864 float4 total
  const float* s; int off;
  if (i < 1048576)      { s = wq; off = i; }
  else if (i < 1310720) { s = wk; off = i - 1048576; }
  else                  { s = wv; off = i - 1310720; }
  float4 v = reinterpret_cast<const float4*>(s)[off];
  uint2 pk; pk.x = pk2bf(v.x, v.y); pk.y = pk2bf(v.z, v.w);
  reinterpret_cast<uint2*>(d)[i] = pk;
}

// ---------------- GEMM: C[M][N] = A[M][K] * B[N][K]^T ----------------
// 128x128 tile, BK=64, global_load_lds staging + XCD-aware block swizzle.
template<int OUT_BF16>
__global__ __launch_bounds__(256, 2) void k_gemm_bt(
    const unsigned short* __restrict__ A,
    const unsigned short* __restrict__ B,
    void* __restrict__ Cv, int M, int N, int K)
{
  constexpr int BK = 64;
  __shared__ __attribute__((aligned(16))) unsigned short smA[128 * BK];
  __shared__ __attribute__((aligned(16))) unsigned short smB[128 * BK];
  const int tid = threadIdx.x;
  const int lane = tid & 63;
  const int wid = tid >> 6;
  const int lr = lane & 15, lg = lane >> 4;
  // XCD swizzle (T1): nwg divisible by 8 for all our grids
  const int gx = gridDim.x;
  int lin = blockIdx.y * gx + blockIdx.x;
  const int cpx = (gx * gridDim.y) >> 3;
  lin = (lin & 7) * cpx + (lin >> 3);
  const int m0 = (lin / gx) * 128, n0 = (lin % gx) * 128;
  const int wr = (wid >> 1) * 64, wc = (wid & 1) * 64;

  f32x4v acc[4][4];
  #pragma unroll
  for (int i = 0; i < 4; i++)
    #pragma unroll
    for (int j = 0; j < 4; j++)
      acc[i][j] = f32x4v{0.f, 0.f, 0.f, 0.f};

  for (int k0 = 0; k0 < K; k0 += BK) {
    #pragma unroll
    for (int c = 0; c < 4; c++) {
      const int chunk = wid * 4 + c;
      const int idx = chunk * 64 + lane;
      const int row = idx >> 3, s = idx & 7;
      const int ks = (s ^ (row & 7)) * 8;
      GLOAD16(A + (size_t)(m0 + row) * K + k0 + ks, &smA[chunk * 512]);
      GLOAD16(B + (size_t)(n0 + row) * K + k0 + ks, &smB[chunk * 512]);
    }
    __syncthreads();
    #pragma unroll
    for (int ks = 0; ks < 2; ks++) {
      bf16x8 af[4], bfv[4];
      #pragma unroll
      for (int m = 0; m < 4; m++)
        af[m] = *reinterpret_cast<const bf16x8*>((char*)smA + swz128(wr + m * 16 + lr, ks * 64 + lg * 16));
      #pragma unroll
      for (int n = 0; n < 4; n++)
        bfv[n] = *reinterpret_cast<const bf16x8*>((char*)smB + swz128(wc + n * 16 + lr, ks * 64 + lg * 16));
      #pragma unroll
      for (int m = 0; m < 4; m++)
        #pragma unroll
        for (int n = 0; n < 4; n++)
          acc[m][n] = __builtin_amdgcn_mfma_f32_16x16x32_bf16(af[m], bfv[n], acc[m][n], 0, 0, 0);
    }
    __syncthreads();
  }
  #pragma unroll
  for (int m = 0; m < 4; m++)
    #pragma unroll
    for (int n = 0; n < 4; n++)
      #pragma unroll
      for (int r = 0; r < 4; r++) {
        const size_t row = m0 + wr + m * 16 + lg * 4 + r;  // C/D: row=(l>>4)*4+r
        const size_t col = n0 + wc + n * 16 + lr;          // col=l&15
        if (OUT_BF16) ((unsigned short*)Cv)[row * N + col] = f2bf(acc[m][n][r]);
        else          ((float*)Cv)[row * N + col] = acc[m][n][r];
      }
}

// ---------------- RoPE Q (scale 1/8 * log2(e) folded: QK^T lands in log2 domain) ----------------
__global__ void k_rope_q(const unsigned short* __restrict__ qkv,
                         const float* __restrict__ fc, const float* __restrict__ fs,
                         unsigned short* __restrict__ Qb)
{
  const int tid = blockIdx.x * 256 + threadIdx.x;
  const int i = tid & 31;
  const int t2 = tid >> 5;
  const int h = t2 & 31;
  const int row = t2 >> 5;
  const int s = row & (SEQLEN - 1);
  const int b = row >> 11;
  const unsigned int u = *reinterpret_cast<const unsigned int*>(qkv + (size_t)row * NQKVC + h * HD + 2 * i);
  const float x0 = bf2f(u & 0xffffu), x1 = bf2f(u >> 16);
  const float c = fc[s * 32 + i], sn = fs[s * 32 + i];
  const float SCL = 0.18033688011112043f;   // 0.125 * log2(e)
  const float o0 = (x0 * c - x1 * sn) * SCL;
  const float o1 = (x0 * sn + x1 * c) * SCL;
  *reinterpret_cast<unsigned int*>(Qb + ((size_t)((b * NH + h) * SEQLEN + s)) * HD + 2 * i) = pk2bf(o0, o1);
}

// ---------------- RoPE K ----------------
__global__ void k_rope_k(const unsigned short* __restrict__ qkv,
                         const float* __restrict__ fc, const float* __restrict__ fs,
                         unsigned short* __restrict__ Kb)
{
  const int tid = blockIdx.x * 256 + threadIdx.x;
  const int i = tid & 31;
  const int t2 = tid >> 5;
  const int kv = t2 & 7;
  const int row = t2 >> 3;
  const int s = row & (SEQLEN - 1);
  const int b = row >> 11;
  const unsigned int u = *reinterpret_cast<const unsigned int*>(
      qkv + (size_t)row * NQKVC + DIMSZ + kv * HD + 2 * i);
  const float x0 = bf2f(u & 0xffffu), x1 = bf2f(u >> 16);
  const float c = fc[s * 32 + i], sn = fs[s * 32 + i];
  const float o0 = x0 * c - x1 * sn;
  const float o1 = x0 * sn + x1 * c;
  *reinterpret_cast<unsigned int*>(Kb + ((size_t)((b * NKV + kv) * SEQLEN + s)) * HD + 2 * i) = pk2bf(o0, o1);
}

// ---------------- V transpose: qkv -> Vt[b][kv][d][s] ----------------
__global__ void k_vt(const unsigned short* __restrict__ qkv, unsigned short* __restrict__ Vt) {
  __shared__ unsigned short tile[64][72];
  const int st = blockIdx.x, kv = blockIdx.y, b = blockIdx.z;
  const int tid = threadIdx.x;
  #pragma unroll
  for (int j2 = 0; j2 < 2; j2++) {
    const int s = (tid >> 3) + j2 * 32, dc = (tid & 7) * 8;
    const int row = b * SEQLEN + st * 64 + s;
    uint4 v = *reinterpret_cast<const uint4*>(
        qkv + (size_t)row * NQKVC + DIMSZ + NKV * HD + kv * HD + dc);
    const unsigned short* vs = reinterpret_cast<const unsigned short*>(&v);
    #pragma unroll
    for (int j = 0; j < 8; j++) tile[s][dc + j] = vs[j];
  }
  __syncthreads();
  {
    const int d = tid >> 2, sc = (tid & 3) * 16;
    unsigned short tmp[16];
    #pragma unroll
    for (int j = 0; j < 16; j++) tmp[j] = tile[sc + j][d];
    unsigned short* outp = Vt + ((size_t)((b * NKV + kv) * HD) + d) * SEQLEN + st * 64 + sc;
    *reinterpret_cast<uint4*>(outp)     = *reinterpret_cast<uint4*>(tmp);
    *reinterpret_cast<uint4*>(outp + 8) = *reinterpret_cast<uint4*>(tmp + 8);
  }
}

// ---------------- flash attention ----------------
// 512 threads = 8 waves x 16 q-rows; q-tile pair (qp, 15-qp). Swapped QK^T
// (S^T = mfma(K,Q)): lane owns one q-row -> in-register softmax, log2 domain.
// Round 6: STATIC double-buffer (4 named LDS arrays, unroll-2 over tiles,
// rule #20) so the compiler can disambiguate prefetch writes from current-
// buffer ds_reads; 1 barrier/tile; prefetch issued BEFORE compute (T3 2-phase).
__global__ __launch_bounds__(512, 2) void k_attn(
    const unsigned short* __restrict__ Qg,   // [B][NH][S][HD], scaled 0.125*log2e
    const unsigned short* __restrict__ Kg,   // [B][NKV][S][HD]
    const unsigned short* __restrict__ Vt,   // [B][NKV][HD][S]
    unsigned short* __restrict__ Og)         // [B*S][NH*HD]
{
  constexpr int KVB = 64;
  __shared__ __attribute__((aligned(16))) unsigned short sK0[KVB * HD];
  __shared__ __attribute__((aligned(16))) unsigned short sK1[KVB * HD];
  __shared__ __attribute__((aligned(16))) unsigned short sV0[HD * KVB];
  __shared__ __attribute__((aligned(16))) unsigned short sV1[HD * KVB];
  __shared__ __attribute__((aligned(16))) unsigned short sP[8 * 16 * KVB];
  const int tid = threadIdx.x;
  const int lane = tid & 63, wid = tid >> 6;
  const int lr = lane & 15, lg = lane >> 4;
  // XCD swizzle: each XCD owns one kv-head panel (~3MB < 4MB L2)
  const int orig = blockIdx.x;                   // 512 blocks, 1-D
  const int w = (orig & 7) * 64 + (orig >> 3);
  const int kvh = w >> 6;
  const int b = (w >> 5) & 1;
  const int h = kvh * 4 + ((w >> 3) & 3);
  const int qp = w & 7;
  const unsigned short* Qp = Qg + ((size_t)(b * NH + h) * SEQLEN) * HD;
  const unsigned short* Kp = Kg + ((size_t)(b * NKV + kvh) * SEQLEN) * HD;
  const unsigned short* Vp = Vt + ((size_t)(b * NKV + kvh) * HD) * SEQLEN;
  unsigned short* Pw = sP + wid * (16 * KVB);

  // staging geometry: wave wid owns 1KB chunk wid of each 8KB tile
  const int sidx = wid * 64 + lane;
  const int srow = sidx >> 3;
  const int scol = ((sidx & 7) ^ (srow & 7)) * 8;

  for (int phase = 0; phase < 2; phase++) {
    const int qt = phase ? (15 - qp) : qp;
    const int qrow0 = qt * 128 + wid * 16;
    bf16x8 aq[2];
    #pragma unroll
    for (int ks = 0; ks < 2; ks++)
      aq[ks] = *reinterpret_cast<const bf16x8*>(Qp + (size_t)(qrow0 + lr) * HD + ks * 32 + lg * 8);

    f32x4v accO[4];
    #pragma unroll
    for (int r = 0; r < 4; r++) accO[r] = f32x4v{0.f, 0.f, 0.f, 0.f};
    float mrun = -3.0e38f, lrun = 0.f;   // softmax state for q = qrow0 + lr (log2 domain)

    auto compute = [&](int kv0, auto& sKb, auto& sVb) {
      if (kv0 > qrow0 + 15) return;      // wave fully masked for this tile
      f32x4v sfr[4];
      #pragma unroll
      for (int c = 0; c < 4; c++) sfr[c] = f32x4v{0.f, 0.f, 0.f, 0.f};
      __builtin_amdgcn_s_setprio(1);
      #pragma unroll
      for (int ks = 0; ks < 2; ks++) {
        bf16x8 bk[4];
        #pragma unroll
        for (int c = 0; c < 4; c++)
          bk[c] = *reinterpret_cast<const bf16x8*>((char*)sKb + swz128(c * 16 + lr, ks * 64 + lg * 16));
        #pragma unroll
        for (int c = 0; c < 4; c++)
          sfr[c] = __builtin_amdgcn_mfma_f32_16x16x32_bf16(bk[c], aq[ks], sfr[c], 0, 0, 0);
      }
      __builtin_amdgcn_s_setprio(0);
      // causal mask: kv = kv0 + c*16 + lg*4 + r, q = qrow0 + lr
      if (kv0 + KVB - 1 > qrow0) {
        const int q = qrow0 + lr;
        #pragma unroll
        for (int c = 0; c < 4; c++)
          #pragma unroll
          for (int r = 0; r < 4; r++) {
            const int kv = kv0 + c * 16 + lg * 4 + r;
            if (kv > q) sfr[c][r] = -1.0e30f;
          }
      }
      // in-register max tree + 2 shfls across lg groups
      float mc[4];
      #pragma unroll
      for (int c = 0; c < 4; c++)
        mc[c] = fmaxf(fmaxf(sfr[c][0], sfr[c][1]), fmaxf(sfr[c][2], sfr[c][3]));
      float tm = fmaxf(fmaxf(mc[0], mc[1]), fmaxf(mc[2], mc[3]));
      tm = fmaxf(tm, __shfl_xor(tm, 16));
      tm = fmaxf(tm, __shfl_xor(tm, 32));
      const float mo = mrun;
      const bool defer = __all(tm <= mo + 8.0f);    // T13, log2 domain
      const float mn = defer ? mo : fmaxf(mo, tm);
      float rc[4];
      #pragma unroll
      for (int c = 0; c < 4; c++) {
        float p0 = __builtin_amdgcn_exp2f(sfr[c][0] - mn);
        float p1 = __builtin_amdgcn_exp2f(sfr[c][1] - mn);
        float p2 = __builtin_amdgcn_exp2f(sfr[c][2] - mn);
        float p3 = __builtin_amdgcn_exp2f(sfr[c][3] - mn);
        sfr[c][0] = p0; sfr[c][1] = p1; sfr[c][2] = p2; sfr[c][3] = p3;
        rc[c] = (p0 + p1) + (p2 + p3);
      }
      float rs = (rc[0] + rc[1]) + (rc[2] + rc[3]);
      rs += __shfl_xor(rs, 16);
      rs += __shfl_xor(rs, 32);
      if (defer) {
        lrun += rs;
      } else {
        const float sc = __builtin_amdgcn_exp2f(mo - mn);
        mrun = mn;
        lrun = lrun * sc + rs;
        #pragma unroll
        for (int r = 0; r < 4; r++) {
          const float scr = __shfl(sc, (lg << 4) + (lg << 2) + r);
          #pragma unroll
          for (int dc = 0; dc < 4; dc++) accO[dc][r] *= scr;
        }
      }
      // P store: lane holds P[q=lr][kv=c*16+lg*4+r] -> 4x packed b64 writes
      #pragma unroll
      for (int c = 0; c < 4; c++) {
        uint2 pk;
        pk.x = pk2bf(sfr[c][0], sfr[c][1]);
        pk.y = pk2bf(sfr[c][2], sfr[c][3]);
        *reinterpret_cast<uint2*>((char*)Pw + swz128(lr, c * 32 + lg * 8)) = pk;
      }
      // O += P V
      __builtin_amdgcn_s_setprio(1);
      #pragma unroll
      for (int ks = 0; ks < 2; ks++) {
        bf16x8 ap = *reinterpret_cast<const bf16x8*>((char*)Pw + swz128(lr, ks * 64 + lg * 16));
        bf16x8 bv[4];
        #pragma unroll
        for (int dc = 0; dc < 4; dc++)
          bv[dc] = *reinterpret_cast<const bf16x8*>((char*)sVb + swz128(dc * 16 + lr, ks * 64 + lg * 16));
        #pragma unroll
        for (int dc = 0; dc < 4; dc++)
          accO[dc] = __builtin_amdgcn_mfma_f32_16x16x32_bf16(ap, bv[dc], accO[dc], 0, 0, 0);
      }
      __builtin_amdgcn_s_setprio(0);
    };

    const int nt = qt * 2 + 2;    // always even
    // prologue: tile 0 -> buffers 0
    GLOAD16(Kp + (size_t)srow * HD + scol, &sK0[wid * 512]);
    GLOAD16(Vp + (size_t)srow * SEQLEN + scol, &sV0[wid * 512]);
    __syncthreads();
    for (int t = 0; t < nt; t += 2) {
      // tile t (buf0); prefetch t+1 -> buf1 (t+1 < nt always: nt even)
      {
        const int kn = (t + 1) * KVB;
        GLOAD16(Kp + (size_t)(kn + srow) * HD + scol, &sK1[wid * 512]);
        GLOAD16(Vp + (size_t)srow * SEQLEN + kn + scol, &sV1[wid * 512]);
      }
      compute(t * KVB, sK0, sV0);
      __syncthreads();
      // tile t+1 (buf1); prefetch t+2 -> buf0
      if (t + 2 < nt) {
        const int kn = (t + 2) * KVB;
        GLOAD16(Kp + (size_t)(kn + srow) * HD + scol, &sK0[wid * 512]);
        GLOAD16(Vp + (size_t)srow * SEQLEN + kn + scol, &sV0[wid * 512]);
      }
      compute((t + 1) * KVB, sK1, sV1);
      __syncthreads();
    }
    // normalize + store (lrun lives at lane q=lr -> shfl to row-domain)
    const float inv = 1.0f / lrun;
    #pragma unroll
    for (int r = 0; r < 4; r++) {
      const float invr = __shfl(inv, (lg << 4) + (lg << 2) + r);
      const int q = qrow0 + lg * 4 + r;
      #pragma unroll
      for (int dc = 0; dc < 4; dc++) {
        const int d = dc * 16 + lr;
        Og[(size_t)(b * SEQLEN + q) * DIMSZ + h * HD + d] = f2bf(accO[dc][r] * invr);
      }
    }
  }
}

extern "C" void kernel_launch(void* const* d_in, const int* in_sizes, int n_in,
                              void* d_out, int out_size, void* d_ws, size_t ws_size,
                              hipStream_t stream)
{
  const float* x  = (const float*)d_in[0];
  const float* fc = (const float*)d_in[1];
  const float* fs = (const float*)d_in[2];
  const float* wq = (const float*)d_in[3];
  const float* wk = (const float*)d_in[4];
  const float* wv = (const float*)d_in[5];
  const float* wo = (const float*)d_in[6];
  float* out = (float*)d_out;
  char* ws = (char*)d_ws;

  unsigned short* xb    = (unsigned short*)(ws + 0);          // [4096][2048]
  unsigned short* wqkvb = (unsigned short*)(ws + 16777216);   // [3072][2048]
  unsigned short* wob   = (unsigned short*)(ws + 29360128);   // [2048][2048]
  unsigned short* qkv   = (unsigned short*)(ws + 37748736);   // [4096][3072]
  unsigned short* Qb    = (unsigned short*)(ws + 62914560);   // [2][32][2048][64]
  unsigned short* Kb    = (unsigned short*)(ws + 79691776);   // [2][8][2048][64]
  unsigned short* Vtb   = (unsigned short*)(ws + 83886080);   // [2][8][64][2048]
  unsigned short* attnb = (unsigned short*)(ws + 88080384);   // [4096][2048]

  k_cvt<<<8192, 256, 0, stream>>>(x,  xb, 2097152);
  k_cvt_w<<<6144, 256, 0, stream>>>(wq, wk, wv, wqkvb);
  k_cvt<<<4096, 256, 0, stream>>>(wo, wob, 1048576);

  dim3 g1(24, 32);   // N=3072/128, M=4096/128
  k_gemm_bt<1><<<g1, 256, 0, stream>>>(xb, wqkvb, qkv, NROWS, NQKVC, DIMSZ);

  k_rope_q<<<16384, 256, 0, stream>>>(qkv, fc, fs, Qb);
  k_rope_k<<<4096, 256, 0, stream>>>(qkv, fc, fs, Kb);
  dim3 gv(32, 8, 2);
  k_vt<<<gv, 256, 0, stream>>>(qkv, Vtb);

  k_attn<<<512, 512, 0, stream>>>(Qb, Kb, Vtb, attnb);

  dim3 g2(16, 32);     // N=2048/128, M=4096/128
  k_gemm_bt<0><<<g2, 256, 0, stream>>>(attnb, wob, out, NROWS, DIMSZ, DIMSZ);
}

// Round 7
// 175.288 us; speedup vs baseline: 1.6251x; 1.0642x over previous
//
#include <hip/hip_runtime.h>

#define DIMSZ 2048
#define NH 32
#define NKV 8
#define HD 64
#define SEQLEN 2048
#define BATCH 2
#define NROWS (BATCH*SEQLEN)   // 4096
#define NQKVC 3072             // 2048 q + 512 k + 512 v

typedef __bf16 bf16x8 __attribute__((ext_vector_type(8)));
typedef __bf16 bf16x2 __attribute__((ext_vector_type(2)));
typedef float f32x4v __attribute__((ext_vector_type(4)));
typedef float f32x2v __attribute__((ext_vector_type(2)));

// scalar f32->bf16 (RTNE) via compiler cast — lowers to v_cvt_pk_bf16_f32 (m240)
__device__ __forceinline__ unsigned short f2bf(float f) {
  __bf16 h = (__bf16)f;
  union { __bf16 h; unsigned short u; } v; v.h = h; return v.u;
}
// packed pair convert: one v_cvt_pk_bf16_f32
__device__ __forceinline__ unsigned int pk2bf(float lo, float hi) {
  f32x2v v; v[0] = lo; v[1] = hi;
  bf16x2 h = __builtin_convertvector(v, bf16x2);
  union { bf16x2 h; unsigned int u; } c; c.h = h; return c.u;
}
__device__ __forceinline__ float bf2f(unsigned int bits16) {
  union { unsigned int u; float f; } v; v.u = bits16 << 16; return v.f;
}
// XOR swizzle for LDS tiles with 128-byte rows.
__device__ __forceinline__ int swz128(int row, int colBytes) {
  return row * 128 + (colBytes ^ ((row & 7) << 4));
}

// async global->LDS, 16B per lane. LDS dest is the wave-uniform chunk base
// (HW adds lane*16); global source is per-lane inverse-swizzled (rule #21).
#define GLOAD16(g, l) __builtin_amdgcn_global_load_lds( \
    (const __attribute__((address_space(1))) unsigned int*)(g), \
    (__attribute__((address_space(3))) unsigned int*)(l), 16, 0, 0)

// ---------------- fp32 -> bf16 convert (vectorized x4) ----------------
__global__ void k_cvt(const float* __restrict__ s, unsigned short* __restrict__ d, int n4) {
  int i = blockIdx.x * 256 + threadIdx.x;
  if (i >= n4) return;
  float4 v = reinterpret_cast<const float4*>(s)[i];
  uint2 pk; pk.x = pk2bf(v.x, v.y); pk.y = pk2bf(v.z, v.w);
  reinterpret_cast<uint2*>(d)[i] = pk;
}

// merged wq|wk|wv convert into contiguous [3072][2048] bf16
__global__ void k_cvt_w(const float* __restrict__ wq, const float* __restrict__ wk,
                        const float* __restrict__ wv, unsigned short* __restrict__ d) {
  int i = blockIdx.x * 256 + threadIdx.x;   // 1572864 float4 total
  const float* s; int off;
  if (i < 1048576)      { s = wq; off = i; }
  else if (i < 1310720) { s = wk; off = i - 1048576; }
  else                  { s = wv; off = i - 1310720; }
  float4 v = reinterpret_cast<const float4*>(s)[off];
  uint2 pk; pk.x = pk2bf(v.x, v.y); pk.y = pk2bf(v.z, v.w);
  reinterpret_cast<uint2*>(d)[i] = pk;
}

// ---------------- QKV GEMM with fused RoPE / V-transpose epilogue ----------------
// C = xb[4096][2048] @ wqkvb[3072][2048]^T. N-blocks are type-pure:
// bx<16 -> Q (rope, scale 0.125*log2e, to Qb[b][h][s][d]),
// bx 16..19 -> K (rope, to Kb[b][kv][s][d]), bx>=20 -> V (to Vt[b][kv][d][s]).
__global__ __launch_bounds__(256, 2) void k_gemm_qkv(
    const unsigned short* __restrict__ A,
    const unsigned short* __restrict__ B,
    const float* __restrict__ fc, const float* __restrict__ fs,
    unsigned short* __restrict__ Qb, unsigned short* __restrict__ Kb,
    unsigned short* __restrict__ Vt)
{
  constexpr int BK = 64, K = DIMSZ, N = NQKVC;
  __shared__ __attribute__((aligned(16))) unsigned short smA[128 * BK];
  __shared__ __attribute__((aligned(16))) unsigned short smB[128 * BK];
  const int tid = threadIdx.x;
  const int lane = tid & 63;
  const int wid = tid >> 6;
  const int lr = lane & 15, lg = lane >> 4;
  const int gx = gridDim.x;
  int lin = blockIdx.y * gx + blockIdx.x;
  const int cpx = (gx * gridDim.y) >> 3;
  lin = (lin & 7) * cpx + (lin >> 3);
  const int m0 = (lin / gx) * 128, n0 = (lin % gx) * 128;
  const int wr = (wid >> 1) * 64, wc = (wid & 1) * 64;

  f32x4v acc[4][4];
  #pragma unroll
  for (int i = 0; i < 4; i++)
    #pragma unroll
    for (int j = 0; j < 4; j++)
      acc[i][j] = f32x4v{0.f, 0.f, 0.f, 0.f};

  for (int k0 = 0; k0 < K; k0 += BK) {
    #pragma unroll
    for (int c = 0; c < 4; c++) {
      const int chunk = wid * 4 + c;
      const int idx = chunk * 64 + lane;
      const int row = idx >> 3, s = idx & 7;
      const int ks = (s ^ (row & 7)) * 8;
      GLOAD16(A + (size_t)(m0 + row) * K + k0 + ks, &smA[chunk * 512]);
      GLOAD16(B + (size_t)(n0 + row) * K + k0 + ks, &smB[chunk * 512]);
    }
    __syncthreads();
    #pragma unroll
    for (int ks = 0; ks < 2; ks++) {
      bf16x8 af[4], bfv[4];
      #pragma unroll
      for (int m = 0; m < 4; m++)
        af[m] = *reinterpret_cast<const bf16x8*>((char*)smA + swz128(wr + m * 16 + lr, ks * 64 + lg * 16));
      #pragma unroll
      for (int n = 0; n < 4; n++)
        bfv[n] = *reinterpret_cast<const bf16x8*>((char*)smB + swz128(wc + n * 16 + lr, ks * 64 + lg * 16));
      #pragma unroll
      for (int m = 0; m < 4; m++)
        #pragma unroll
        for (int n = 0; n < 4; n++)
          acc[m][n] = __builtin_amdgcn_mfma_f32_16x16x32_bf16(af[m], bfv[n], acc[m][n], 0, 0, 0);
    }
    __syncthreads();
  }
  // ---- fused epilogue (C/D layout: row=(l>>4)*4+r, col=l&15) ----
  const int bx = n0 >> 7;
  if (bx < 20) {
    // Q or K: RoPE. pair (2i,2i+1) lives in adjacent lanes -> shfl_xor(1).
    const bool isQ = bx < 16;
    const float SCL = isQ ? 0.18033688011112043f : 1.0f;   // 0.125*log2(e) for Q
    #pragma unroll
    for (int n = 0; n < 4; n++) {
      const int col = n0 + wc + n * 16 + lr;
      const int d = col & 63;
      const int i = d >> 1;
      const float sgn = (d & 1) ? 1.0f : -1.0f;
      unsigned short* dst;
      if (isQ) dst = Qb + (size_t)(col >> 6) * (SEQLEN * HD) + d;                  // + (b*NH)*... below
      else     dst = Kb + (size_t)((col - 2048) >> 6) * (SEQLEN * HD) + d;
      #pragma unroll
      for (int m = 0; m < 4; m++)
        #pragma unroll
        for (int r = 0; r < 4; r++) {
          const int row = m0 + wr + m * 16 + lg * 4 + r;
          const int s = row & (SEQLEN - 1), b = row >> 11;
          const float v = acc[m][n][r];
          const float p = __shfl_xor(v, 1);
          const float c = fc[s * 32 + i], sn = fs[s * 32 + i];
          const float o = (v * c + sgn * p * sn) * SCL;
          const size_t headStride = (size_t)(isQ ? NH : NKV) * SEQLEN * HD;
          dst[(size_t)b * headStride + (size_t)s * HD] = f2bf(o);
        }
    }
  } else {
    // V: write transposed [b][kv][d][s]; r=0..3 -> consecutive s -> 8B pack
    #pragma unroll
    for (int n = 0; n < 4; n++) {
      const int col = n0 + wc + n * 16 + lr;
      const int kvh = (col - 2560) >> 6, d = col & 63;
      #pragma unroll
      for (int m = 0; m < 4; m++) {
        const int row0 = m0 + wr + m * 16 + lg * 4;
        const int s0 = row0 & (SEQLEN - 1), b = row0 >> 11;
        uint2 pk;
        pk.x = pk2bf(acc[m][n][0], acc[m][n][1]);
        pk.y = pk2bf(acc[m][n][2], acc[m][n][3]);
        *reinterpret_cast<uint2*>(
            Vt + ((size_t)((b * NKV + kvh) * HD) + d) * SEQLEN + s0) = pk;
      }
    }
  }
}

// ---------------- GEMM: C[M][N] = A[M][K] * B[N][K]^T (O-projection) ----------------
template<int OUT_BF16>
__global__ __launch_bounds__(256, 2) void k_gemm_bt(
    const unsigned short* __restrict__ A,
    const unsigned short* __restrict__ B,
    void* __restrict__ Cv, int M, int N, int K)
{
  constexpr int BK = 64;
  __shared__ __attribute__((aligned(16))) unsigned short smA[128 * BK];
  __shared__ __attribute__((aligned(16))) unsigned short smB[128 * BK];
  const int tid = threadIdx.x;
  const int lane = tid & 63;
  const int wid = tid >> 6;
  const int lr = lane & 15, lg = lane >> 4;
  const int gx = gridDim.x;
  int lin = blockIdx.y * gx + blockIdx.x;
  const int cpx = (gx * gridDim.y) >> 3;
  lin = (lin & 7) * cpx + (lin >> 3);
  const int m0 = (lin / gx) * 128, n0 = (lin % gx) * 128;
  const int wr = (wid >> 1) * 64, wc = (wid & 1) * 64;

  f32x4v acc[4][4];
  #pragma unroll
  for (int i = 0; i < 4; i++)
    #pragma unroll
    for (int j = 0; j < 4; j++)
      acc[i][j] = f32x4v{0.f, 0.f, 0.f, 0.f};

  for (int k0 = 0; k0 < K; k0 += BK) {
    #pragma unroll
    for (int c = 0; c < 4; c++) {
      const int chunk = wid * 4 + c;
      const int idx = chunk * 64 + lane;
      const int row = idx >> 3, s = idx & 7;
      const int ks = (s ^ (row & 7)) * 8;
      GLOAD16(A + (size_t)(m0 + row) * K + k0 + ks, &smA[chunk * 512]);
      GLOAD16(B + (size_t)(n0 + row) * K + k0 + ks, &smB[chunk * 512]);
    }
    __syncthreads();
    #pragma unroll
    for (int ks = 0; ks < 2; ks++) {
      bf16x8 af[4], bfv[4];
      #pragma unroll
      for (int m = 0; m < 4; m++)
        af[m] = *reinterpret_cast<const bf16x8*>((char*)smA + swz128(wr + m * 16 + lr, ks * 64 + lg * 16));
      #pragma unroll
      for (int n = 0; n < 4; n++)
        bfv[n] = *reinterpret_cast<const bf16x8*>((char*)smB + swz128(wc + n * 16 + lr, ks * 64 + lg * 16));
      #pragma unroll
      for (int m = 0; m < 4; m++)
        #pragma unroll
        for (int n = 0; n < 4; n++)
          acc[m][n] = __builtin_amdgcn_mfma_f32_16x16x32_bf16(af[m], bfv[n], acc[m][n], 0, 0, 0);
    }
    __syncthreads();
  }
  #pragma unroll
  for (int m = 0; m < 4; m++)
    #pragma unroll
    for (int n = 0; n < 4; n++)
      #pragma unroll
      for (int r = 0; r < 4; r++) {
        const size_t row = m0 + wr + m * 16 + lg * 4 + r;  // C/D: row=(l>>4)*4+r
        const size_t col = n0 + wc + n * 16 + lr;          // col=l&15
        if (OUT_BF16) ((unsigned short*)Cv)[row * N + col] = f2bf(acc[m][n][r]);
        else          ((float*)Cv)[row * N + col] = acc[m][n][r];
      }
}

// ---------------- flash attention (unchanged from round 6) ----------------
__global__ __launch_bounds__(512, 2) void k_attn(
    const unsigned short* __restrict__ Qg,   // [B][NH][S][HD], scaled 0.125*log2e
    const unsigned short* __restrict__ Kg,   // [B][NKV][S][HD]
    const unsigned short* __restrict__ Vt,   // [B][NKV][HD][S]
    unsigned short* __restrict__ Og)         // [B*S][NH*HD]
{
  constexpr int KVB = 64;
  __shared__ __attribute__((aligned(16))) unsigned short sK0[KVB * HD];
  __shared__ __attribute__((aligned(16))) unsigned short sK1[KVB * HD];
  __shared__ __attribute__((aligned(16))) unsigned short sV0[HD * KVB];
  __shared__ __attribute__((aligned(16))) unsigned short sV1[HD * KVB];
  __shared__ __attribute__((aligned(16))) unsigned short sP[8 * 16 * KVB];
  const int tid = threadIdx.x;
  const int lane = tid & 63, wid = tid >> 6;
  const int lr = lane & 15, lg = lane >> 4;
  const int orig = blockIdx.x;                   // 512 blocks, 1-D
  const int w = (orig & 7) * 64 + (orig >> 3);
  const int kvh = w >> 6;
  const int b = (w >> 5) & 1;
  const int h = kvh * 4 + ((w >> 3) & 3);
  const int qp = w & 7;
  const unsigned short* Qp = Qg + ((size_t)(b * NH + h) * SEQLEN) * HD;
  const unsigned short* Kp = Kg + ((size_t)(b * NKV + kvh) * SEQLEN) * HD;
  const unsigned short* Vp = Vt + ((size_t)(b * NKV + kvh) * HD) * SEQLEN;
  unsigned short* Pw = sP + wid * (16 * KVB);

  const int sidx = wid * 64 + lane;
  const int srow = sidx >> 3;
  const int scol = ((sidx & 7) ^ (srow & 7)) * 8;

  for (int phase = 0; phase < 2; phase++) {
    const int qt = phase ? (15 - qp) : qp;
    const int qrow0 = qt * 128 + wid * 16;
    bf16x8 aq[2];
    #pragma unroll
    for (int ks = 0; ks < 2; ks++)
      aq[ks] = *reinterpret_cast<const bf16x8*>(Qp + (size_t)(qrow0 + lr) * HD + ks * 32 + lg * 8);

    f32x4v accO[4];
    #pragma unroll
    for (int r = 0; r < 4; r++) accO[r] = f32x4v{0.f, 0.f, 0.f, 0.f};
    float mrun = -3.0e38f, lrun = 0.f;   // softmax state for q = qrow0 + lr (log2 domain)

    auto compute = [&](int kv0, auto& sKb, auto& sVb) {
      if (kv0 > qrow0 + 15) return;
      f32x4v sfr[4];
      #pragma unroll
      for (int c = 0; c < 4; c++) sfr[c] = f32x4v{0.f, 0.f, 0.f, 0.f};
      __builtin_amdgcn_s_setprio(1);
      #pragma unroll
      for (int ks = 0; ks < 2; ks++) {
        bf16x8 bk[4];
        #pragma unroll
        for (int c = 0; c < 4; c++)
          bk[c] = *reinterpret_cast<const bf16x8*>((char*)sKb + swz128(c * 16 + lr, ks * 64 + lg * 16));
        #pragma unroll
        for (int c = 0; c < 4; c++)
          sfr[c] = __builtin_amdgcn_mfma_f32_16x16x32_bf16(bk[c], aq[ks], sfr[c], 0, 0, 0);
      }
      __builtin_amdgcn_s_setprio(0);
      if (kv0 + KVB - 1 > qrow0) {
        const int q = qrow0 + lr;
        #pragma unroll
        for (int c = 0; c < 4; c++)
          #pragma unroll
          for (int r = 0; r < 4; r++) {
            const int kv = kv0 + c * 16 + lg * 4 + r;
            if (kv > q) sfr[c][r] = -1.0e30f;
          }
      }
      float mc[4];
      #pragma unroll
      for (int c = 0; c < 4; c++)
        mc[c] = fmaxf(fmaxf(sfr[c][0], sfr[c][1]), fmaxf(sfr[c][2], sfr[c][3]));
      float tm = fmaxf(fmaxf(mc[0], mc[1]), fmaxf(mc[2], mc[3]));
      tm = fmaxf(tm, __shfl_xor(tm, 16));
      tm = fmaxf(tm, __shfl_xor(tm, 32));
      const float mo = mrun;
      const bool defer = __all(tm <= mo + 8.0f);    // T13, log2 domain
      const float mn = defer ? mo : fmaxf(mo, tm);
      float rc[4];
      #pragma unroll
      for (int c = 0; c < 4; c++) {
        float p0 = __builtin_amdgcn_exp2f(sfr[c][0] - mn);
        float p1 = __builtin_amdgcn_exp2f(sfr[c][1] - mn);
        float p2 = __builtin_amdgcn_exp2f(sfr[c][2] - mn);
        float p3 = __builtin_amdgcn_exp2f(sfr[c][3] - mn);
        sfr[c][0] = p0; sfr[c][1] = p1; sfr[c][2] = p2; sfr[c][3] = p3;
        rc[c] = (p0 + p1) + (p2 + p3);
      }
      float rs = (rc[0] + rc[1]) + (rc[2] + rc[3]);
      rs += __shfl_xor(rs, 16);
      rs += __shfl_xor(rs, 32);
      if (defer) {
        lrun += rs;
      } else {
        const float sc = __builtin_amdgcn_exp2f(mo - mn);
        mrun = mn;
        lrun = lrun * sc + rs;
        #pragma unroll
        for (int r = 0; r < 4; r++) {
          const float scr = __shfl(sc, (lg << 4) + (lg << 2) + r);
          #pragma unroll
          for (int dc = 0; dc < 4; dc++) accO[dc][r] *= scr;
        }
      }
      #pragma unroll
      for (int c = 0; c < 4; c++) {
        uint2 pk;
        pk.x = pk2bf(sfr[c][0], sfr[c][1]);
        pk.y = pk2bf(sfr[c][2], sfr[c][3]);
        *reinterpret_cast<uint2*>((char*)Pw + swz128(lr, c * 32 + lg * 8)) = pk;
      }
      __builtin_amdgcn_s_setprio(1);
      #pragma unroll
      for (int ks = 0; ks < 2; ks++) {
        bf16x8 ap = *reinterpret_cast<const bf16x8*>((char*)Pw + swz128(lr, ks * 64 + lg * 16));
        bf16x8 bv[4];
        #pragma unroll
        for (int dc = 0; dc < 4; dc++)
          bv[dc] = *reinterpret_cast<const bf16x8*>((char*)sVb + swz128(dc * 16 + lr, ks * 64 + lg * 16));
        #pragma unroll
        for (int dc = 0; dc < 4; dc++)
          accO[dc] = __builtin_amdgcn_mfma_f32_16x16x32_bf16(ap, bv[dc], accO[dc], 0, 0, 0);
      }
      __builtin_amdgcn_s_setprio(0);
    };

    const int nt = qt * 2 + 2;    // always even
    GLOAD16(Kp + (size_t)srow * HD + scol, &sK0[wid * 512]);
    GLOAD16(Vp + (size_t)srow * SEQLEN + scol, &sV0[wid * 512]);
    __syncthreads();
    for (int t = 0; t < nt; t += 2) {
      {
        const int kn = (t + 1) * KVB;
        GLOAD16(Kp + (size_t)(kn + srow) * HD + scol, &sK1[wid * 512]);
        GLOAD16(Vp + (size_t)srow * SEQLEN + kn + scol, &sV1[wid * 512]);
      }
      compute(t * KVB, sK0, sV0);
      __syncthreads();
      if (t + 2 < nt) {
        const int kn = (t + 2) * KVB;
        GLOAD16(Kp + (size_t)(kn + srow) * HD + scol, &sK0[wid * 512]);
        GLOAD16(Vp + (size_t)srow * SEQLEN + kn + scol, &sV0[wid * 512]);
      }
      compute((t + 1) * KVB, sK1, sV1);
      __syncthreads();
    }
    const float inv = 1.0f / lrun;
    #pragma unroll
    for (int r = 0; r < 4; r++) {
      const float invr = __shfl(inv, (lg << 4) + (lg << 2) + r);
      const int q = qrow0 + lg * 4 + r;
      #pragma unroll
      for (int dc = 0; dc < 4; dc++) {
        const int d = dc * 16 + lr;
        Og[(size_t)(b * SEQLEN + q) * DIMSZ + h * HD + d] = f2bf(accO[dc][r] * invr);
      }
    }
  }
}

extern "C" void kernel_launch(void* const* d_in, const int* in_sizes, int n_in,
                              void* d_out, int out_size, void* d_ws, size_t ws_size,
                              hipStream_t stream)
{
  const float* x  = (const float*)d_in[0];
  const float* fc = (const float*)d_in[1];
  const float* fs = (const float*)d_in[2];
  const float* wq = (const float*)d_in[3];
  const float* wk = (const float*)d_in[4];
  const float* wv = (const float*)d_in[5];
  const float* wo = (const float*)d_in[6];
  float* out = (float*)d_out;
  char* ws = (char*)d_ws;

  unsigned short* xb    = (unsigned short*)(ws + 0);          // [4096][2048]
  unsigned short* wqkvb = (unsigned short*)(ws + 16777216);   // [3072][2048]
  unsigned short* wob   = (unsigned short*)(ws + 29360128);   // [2048][2048]
  unsigned short* Qb    = (unsigned short*)(ws + 62914560);   // [2][32][2048][64]
  unsigned short* Kb    = (unsigned short*)(ws + 79691776);   // [2][8][2048][64]
  unsigned short* Vtb   = (unsigned short*)(ws + 83886080);   // [2][8][64][2048]
  unsigned short* attnb = (unsigned short*)(ws + 88080384);   // [4096][2048]

  k_cvt<<<8192, 256, 0, stream>>>(x,  xb, 2097152);
  k_cvt_w<<<6144, 256, 0, stream>>>(wq, wk, wv, wqkvb);
  k_cvt<<<4096, 256, 0, stream>>>(wo, wob, 1048576);

  dim3 g1(24, 32);   // N=3072/128, M=4096/128 — fused RoPE/Vt epilogue
  k_gemm_qkv<<<g1, 256, 0, stream>>>(xb, wqkvb, fc, fs, Qb, Kb, Vtb);

  k_attn<<<512, 512, 0, stream>>>(Qb, Kb, Vtb, attnb);

  dim3 g2(16, 32);     // N=2048/128, M=4096/128
  k_gemm_bt<0><<<g2, 256, 0, stream>>>(attnb, wob, out, NROWS, DIMSZ, DIMSZ);
}

// Round 8
// 171.083 us; speedup vs baseline: 1.6650x; 1.0246x over previous
//
#include <hip/hip_runtime.h>

#define DIMSZ 2048
#define NH 32
#define NKV 8
#define HD 64
#define SEQLEN 2048
#define BATCH 2
#define NROWS (BATCH*SEQLEN)   // 4096
#define NQKVC 3072             // 2048 q + 512 k + 512 v

typedef __bf16 bf16x8 __attribute__((ext_vector_type(8)));
typedef __bf16 bf16x2 __attribute__((ext_vector_type(2)));
typedef float f32x4v __attribute__((ext_vector_type(4)));
typedef float f32x2v __attribute__((ext_vector_type(2)));
typedef float f32x16 __attribute__((ext_vector_type(16)));

__device__ __forceinline__ unsigned short f2bf(float f) {
  __bf16 h = (__bf16)f;
  union { __bf16 h; unsigned short u; } v; v.h = h; return v.u;
}
__device__ __forceinline__ unsigned int pk2bf(float lo, float hi) {
  f32x2v v; v[0] = lo; v[1] = hi;
  bf16x2 h = __builtin_convertvector(v, bf16x2);
  union { bf16x2 h; unsigned int u; } c; c.h = h; return c.u;
}
__device__ __forceinline__ float bf2f(unsigned int bits16) {
  union { unsigned int u; float f; } v; v.u = bits16 << 16; return v.f;
}
// XOR swizzle for LDS tiles with 128-byte rows.
__device__ __forceinline__ int swz128(int row, int colBytes) {
  return row * 128 + (colBytes ^ ((row & 7) << 4));
}

#define GLOAD16(g, l) __builtin_amdgcn_global_load_lds( \
    (const __attribute__((address_space(1))) unsigned int*)(g), \
    (__attribute__((address_space(3))) unsigned int*)(l), 16, 0, 0)

// ---------------- merged fp32 -> bf16 convert (x | wq|wk|wv | wo) ----------------
__global__ void k_cvt_all(const float* __restrict__ x,
                          const float* __restrict__ wq, const float* __restrict__ wk,
                          const float* __restrict__ wv, const float* __restrict__ wo,
                          unsigned short* __restrict__ xb,
                          unsigned short* __restrict__ wqkvb,
                          unsigned short* __restrict__ wob) {
  int i = blockIdx.x * 256 + threadIdx.x;   // 4,718,592 float4 total
  const float* s; unsigned short* d; int off;
  if (i < 2097152)      { s = x;  d = xb;    off = i; }
  else {
    int j = i - 2097152;
    if (j < 1048576)      { s = wq; d = wqkvb; off = j; }
    else if (j < 1310720) { s = wk; d = wqkvb; off = j; s = wk; off = j; }
    else if (j < 1572864) { s = wv; d = wqkvb; off = j; }
    else                  { s = wo; d = wob;   off = j - 1572864; }
    if (j >= 1048576 && j < 1310720) { /* wk source offset */ }
  }
  // recompute clean source offsets for the weight segments
  if (i >= 2097152) {
    int j = i - 2097152;
    if (j < 1048576)      { s = wq; off = j;            d = wqkvb; }
    else if (j < 1310720) { s = wk; off = j - 1048576;  d = wqkvb; off += 0; }
    else if (j < 1572864) { s = wv; off = j - 1310720;  d = wqkvb; }
    else                  { s = wo; off = j - 1572864;  d = wob; }
    float4 v = reinterpret_cast<const float4*>(s)[off];
    uint2 pk; pk.x = pk2bf(v.x, v.y); pk.y = pk2bf(v.z, v.w);
    int dsti = (j < 1572864) ? j : (j - 1572864);
    reinterpret_cast<uint2*>(d)[dsti] = pk;
  } else {
    float4 v = reinterpret_cast<const float4*>(x)[i];
    uint2 pk; pk.x = pk2bf(v.x, v.y); pk.y = pk2bf(v.z, v.w);
    reinterpret_cast<uint2*>(xb)[i] = pk;
  }
}

// ---------------- QKV GEMM with fused RoPE / V-transpose epilogue ----------------
__global__ __launch_bounds__(256, 2) void k_gemm_qkv(
    const unsigned short* __restrict__ A,
    const unsigned short* __restrict__ B,
    const float* __restrict__ fc, const float* __restrict__ fs,
    unsigned short* __restrict__ Qb, unsigned short* __restrict__ Kb,
    unsigned short* __restrict__ Vt)
{
  constexpr int BK = 64, K = DIMSZ;
  __shared__ __attribute__((aligned(16))) unsigned short smA[128 * BK];
  __shared__ __attribute__((aligned(16))) unsigned short smB[128 * BK];
  const int tid = threadIdx.x;
  const int lane = tid & 63;
  const int wid = tid >> 6;
  const int lr = lane & 15, lg = lane >> 4;
  const int gx = gridDim.x;
  int lin = blockIdx.y * gx + blockIdx.x;
  const int cpx = (gx * gridDim.y) >> 3;
  lin = (lin & 7) * cpx + (lin >> 3);
  const int m0 = (lin / gx) * 128, n0 = (lin % gx) * 128;
  const int wr = (wid >> 1) * 64, wc = (wid & 1) * 64;

  f32x4v acc[4][4];
  #pragma unroll
  for (int i = 0; i < 4; i++)
    #pragma unroll
    for (int j = 0; j < 4; j++)
      acc[i][j] = f32x4v{0.f, 0.f, 0.f, 0.f};

  for (int k0 = 0; k0 < K; k0 += BK) {
    #pragma unroll
    for (int c = 0; c < 4; c++) {
      const int chunk = wid * 4 + c;
      const int idx = chunk * 64 + lane;
      const int row = idx >> 3, s = idx & 7;
      const int ks = (s ^ (row & 7)) * 8;
      GLOAD16(A + (size_t)(m0 + row) * K + k0 + ks, &smA[chunk * 512]);
      GLOAD16(B + (size_t)(n0 + row) * K + k0 + ks, &smB[chunk * 512]);
    }
    __syncthreads();
    #pragma unroll
    for (int ks = 0; ks < 2; ks++) {
      bf16x8 af[4], bfv[4];
      #pragma unroll
      for (int m = 0; m < 4; m++)
        af[m] = *reinterpret_cast<const bf16x8*>((char*)smA + swz128(wr + m * 16 + lr, ks * 64 + lg * 16));
      #pragma unroll
      for (int n = 0; n < 4; n++)
        bfv[n] = *reinterpret_cast<const bf16x8*>((char*)smB + swz128(wc + n * 16 + lr, ks * 64 + lg * 16));
      #pragma unroll
      for (int m = 0; m < 4; m++)
        #pragma unroll
        for (int n = 0; n < 4; n++)
          acc[m][n] = __builtin_amdgcn_mfma_f32_16x16x32_bf16(af[m], bfv[n], acc[m][n], 0, 0, 0);
    }
    __syncthreads();
  }
  const int bx = n0 >> 7;
  if (bx < 20) {
    const bool isQ = bx < 16;
    const float SCL = isQ ? 0.18033688011112043f : 1.0f;   // 0.125*log2(e) for Q
    #pragma unroll
    for (int n = 0; n < 4; n++) {
      const int col = n0 + wc + n * 16 + lr;
      const int d = col & 63;
      const int i = d >> 1;
      const float sgn = (d & 1) ? 1.0f : -1.0f;
      unsigned short* dst;
      if (isQ) dst = Qb + (size_t)(col >> 6) * (SEQLEN * HD) + d;
      else     dst = Kb + (size_t)((col - 2048) >> 6) * (SEQLEN * HD) + d;
      #pragma unroll
      for (int m = 0; m < 4; m++)
        #pragma unroll
        for (int r = 0; r < 4; r++) {
          const int row = m0 + wr + m * 16 + lg * 4 + r;
          const int s = row & (SEQLEN - 1), b = row >> 11;
          const float v = acc[m][n][r];
          const float p = __shfl_xor(v, 1);
          const float c = fc[s * 32 + i], sn = fs[s * 32 + i];
          const float o = (v * c + sgn * p * sn) * SCL;
          const size_t headStride = (size_t)(isQ ? NH : NKV) * SEQLEN * HD;
          dst[(size_t)b * headStride + (size_t)s * HD] = f2bf(o);
        }
    }
  } else {
    #pragma unroll
    for (int n = 0; n < 4; n++) {
      const int col = n0 + wc + n * 16 + lr;
      const int kvh = (col - 2560) >> 6, d = col & 63;
      #pragma unroll
      for (int m = 0; m < 4; m++) {
        const int row0 = m0 + wr + m * 16 + lg * 4;
        const int s0 = row0 & (SEQLEN - 1), b = row0 >> 11;
        uint2 pk;
        pk.x = pk2bf(acc[m][n][0], acc[m][n][1]);
        pk.y = pk2bf(acc[m][n][2], acc[m][n][3]);
        *reinterpret_cast<uint2*>(
            Vt + ((size_t)((b * NKV + kvh) * HD) + d) * SEQLEN + s0) = pk;
      }
    }
  }
}

// ---------------- GEMM: C[M][N] = A[M][K] * B[N][K]^T (O-projection) ----------------
template<int OUT_BF16>
__global__ __launch_bounds__(256, 2) void k_gemm_bt(
    const unsigned short* __restrict__ A,
    const unsigned short* __restrict__ B,
    void* __restrict__ Cv, int M, int N, int K)
{
  constexpr int BK = 64;
  __shared__ __attribute__((aligned(16))) unsigned short smA[128 * BK];
  __shared__ __attribute__((aligned(16))) unsigned short smB[128 * BK];
  const int tid = threadIdx.x;
  const int lane = tid & 63;
  const int wid = tid >> 6;
  const int lr = lane & 15, lg = lane >> 4;
  const int gx = gridDim.x;
  int lin = blockIdx.y * gx + blockIdx.x;
  const int cpx = (gx * gridDim.y) >> 3;
  lin = (lin & 7) * cpx + (lin >> 3);
  const int m0 = (lin / gx) * 128, n0 = (lin % gx) * 128;
  const int wr = (wid >> 1) * 64, wc = (wid & 1) * 64;

  f32x4v acc[4][4];
  #pragma unroll
  for (int i = 0; i < 4; i++)
    #pragma unroll
    for (int j = 0; j < 4; j++)
      acc[i][j] = f32x4v{0.f, 0.f, 0.f, 0.f};

  for (int k0 = 0; k0 < K; k0 += BK) {
    #pragma unroll
    for (int c = 0; c < 4; c++) {
      const int chunk = wid * 4 + c;
      const int idx = chunk * 64 + lane;
      const int row = idx >> 3, s = idx & 7;
      const int ks = (s ^ (row & 7)) * 8;
      GLOAD16(A + (size_t)(m0 + row) * K + k0 + ks, &smA[chunk * 512]);
      GLOAD16(B + (size_t)(n0 + row) * K + k0 + ks, &smB[chunk * 512]);
    }
    __syncthreads();
    #pragma unroll
    for (int ks = 0; ks < 2; ks++) {
      bf16x8 af[4], bfv[4];
      #pragma unroll
      for (int m = 0; m < 4; m++)
        af[m] = *reinterpret_cast<const bf16x8*>((char*)smA + swz128(wr + m * 16 + lr, ks * 64 + lg * 16));
      #pragma unroll
      for (int n = 0; n < 4; n++)
        bfv[n] = *reinterpret_cast<const bf16x8*>((char*)smB + swz128(wc + n * 16 + lr, ks * 64 + lg * 16));
      #pragma unroll
      for (int m = 0; m < 4; m++)
        #pragma unroll
        for (int n = 0; n < 4; n++)
          acc[m][n] = __builtin_amdgcn_mfma_f32_16x16x32_bf16(af[m], bfv[n], acc[m][n], 0, 0, 0);
    }
    __syncthreads();
  }
  #pragma unroll
  for (int m = 0; m < 4; m++)
    #pragma unroll
    for (int n = 0; n < 4; n++)
      #pragma unroll
      for (int r = 0; r < 4; r++) {
        const size_t row = m0 + wr + m * 16 + lg * 4 + r;
        const size_t col = n0 + wc + n * 16 + lr;
        if (OUT_BF16) ((unsigned short*)Cv)[row * N + col] = f2bf(acc[m][n][r]);
        else          ((float*)Cv)[row * N + col] = acc[m][n][r];
      }
}

// ---------------- flash attention: 32x32 MFMA, 4 waves x 32 q-rows ----------------
// Swapped QK^T (S^T = mfma(K,Q), 32x32x16): lane owns q=lane&31 (paired with
// lane^32 holding the complementary kv halves). Softmax fully in-register:
// 31-op max/sum trees + 1 shfl_xor(32). P never touches LDS: PV A-fragments
// built via cvt_pk + shfl_xor(32) (T12). Static dbuf K/V staging (round-6).
// C/D 32x32 layout (m74/m101): col=lane&31, row=(reg&3)+8*(reg>>2)+4*(lane>>5).
__global__ __launch_bounds__(256, 2) void k_attn(
    const unsigned short* __restrict__ Qg,   // [B][NH][S][HD], scaled 0.125*log2e
    const unsigned short* __restrict__ Kg,   // [B][NKV][S][HD]
    const unsigned short* __restrict__ Vt,   // [B][NKV][HD][S]
    unsigned short* __restrict__ Og)         // [B*S][NH*HD]
{
  constexpr int KVB = 64;
  __shared__ __attribute__((aligned(16))) unsigned short sK0[KVB * HD];
  __shared__ __attribute__((aligned(16))) unsigned short sK1[KVB * HD];
  __shared__ __attribute__((aligned(16))) unsigned short sV0[HD * KVB];
  __shared__ __attribute__((aligned(16))) unsigned short sV1[HD * KVB];
  const int tid = threadIdx.x;
  const int lane = tid & 63, wid = tid >> 6;       // 4 waves
  const int l31 = lane & 31, hi = lane >> 5;
  // XCD swizzle: each XCD owns one kv-head panel
  const int orig = blockIdx.x;                     // 512 blocks
  const int w = (orig & 7) * 64 + (orig >> 3);
  const int kvh = w >> 6;
  const int b = (w >> 5) & 1;
  const int h = kvh * 4 + ((w >> 3) & 3);
  const int qp = w & 7;
  const unsigned short* Qp = Qg + ((size_t)(b * NH + h) * SEQLEN) * HD;
  const unsigned short* Kp = Kg + ((size_t)(b * NKV + kvh) * SEQLEN) * HD;
  const unsigned short* Vp = Vt + ((size_t)(b * NKV + kvh) * HD) * SEQLEN;

  // staging: 8 chunks of 1KB per 8KB tile; wave wid owns chunks 2wid, 2wid+1
  int srow[2], scol[2];
  #pragma unroll
  for (int c = 0; c < 2; c++) {
    const int idx = (wid * 2 + c) * 64 + lane;
    srow[c] = idx >> 3;
    scol[c] = ((idx & 7) ^ (srow[c] & 7)) * 8;
  }

  for (int phase = 0; phase < 2; phase++) {
    const int qt = phase ? (15 - qp) : qp;
    const int qrow0 = qt * 128 + wid * 32;
    const int qg = qrow0 + l31;                    // this lane's q-row (local in S)
    bf16x8 aq[4];                                  // Q B-frags: k-slice ks*16+hi*8
    #pragma unroll
    for (int ks = 0; ks < 4; ks++)
      aq[ks] = *reinterpret_cast<const bf16x8*>(Qp + (size_t)qg * HD + ks * 16 + hi * 8);

    f32x16 accO0, accO1;
    #pragma unroll
    for (int i = 0; i < 16; i++) { accO0[i] = 0.f; accO1[i] = 0.f; }
    float mrun = -3.0e38f, lrun = 0.f;             // log2-domain state for q=qg

    auto compute = [&](int kv0, auto& sKb, auto& sVb) {
      if (kv0 > qrow0 + 31) return;
      f32x16 S0, S1;
      #pragma unroll
      for (int i = 0; i < 16; i++) { S0[i] = 0.f; S1[i] = 0.f; }
      __builtin_amdgcn_s_setprio(1);
      #pragma unroll
      for (int ks = 0; ks < 4; ks++) {
        bf16x8 ak0 = *reinterpret_cast<const bf16x8*>((char*)sKb + swz128(l31,      ks * 32 + hi * 16));
        bf16x8 ak1 = *reinterpret_cast<const bf16x8*>((char*)sKb + swz128(32 + l31, ks * 32 + hi * 16));
        S0 = __builtin_amdgcn_mfma_f32_32x32x16_bf16(ak0, aq[ks], S0, 0, 0, 0);
        S1 = __builtin_amdgcn_mfma_f32_32x32x16_bf16(ak1, aq[ks], S1, 0, 0, 0);
      }
      __builtin_amdgcn_s_setprio(0);
      if (kv0 + KVB - 1 > qrow0) {                 // boundary tile: causal mask
        #pragma unroll
        for (int reg = 0; reg < 16; reg++) {
          const int rl = (reg & 3) + 8 * (reg >> 2) + (hi << 2);
          if (kv0 + rl > qg)      S0[reg] = -1.0e30f;
          if (kv0 + 32 + rl > qg) S1[reg] = -1.0e30f;
        }
      }
      // row max: 31 in-register + 1 cross-half exchange
      float tm = S0[0];
      #pragma unroll
      for (int i = 1; i < 16; i++) tm = fmaxf(tm, S0[i]);
      #pragma unroll
      for (int i = 0; i < 16; i++) tm = fmaxf(tm, S1[i]);
      tm = fmaxf(tm, __shfl_xor(tm, 32));
      const float mo = mrun;
      const bool defer = __all(tm <= mo + 8.0f);   // T13, log2 domain
      const float mn = defer ? mo : fmaxf(mo, tm);
      #pragma unroll
      for (int i = 0; i < 16; i++) {
        S0[i] = __builtin_amdgcn_exp2f(S0[i] - mn);
        S1[i] = __builtin_amdgcn_exp2f(S1[i] - mn);
      }
      float rs = 0.f;
      #pragma unroll
      for (int i = 0; i < 16; i++) rs += S0[i] + S1[i];
      rs += __shfl_xor(rs, 32);
      if (defer) {
        lrun += rs;
      } else {
        const float sc = __builtin_amdgcn_exp2f(mo - mn);
        mrun = mn;
        lrun = lrun * sc + rs;
        #pragma unroll
        for (int reg = 0; reg < 16; reg++) {
          const int rl = (reg & 3) + 8 * (reg >> 2) + (hi << 2);
          const float scr = __shfl(sc, rl);
          accO0[reg] *= scr; accO1[reg] *= scr;
        }
      }
      // PV: build A-frags in-register (T12) and accumulate O[q][d]
      __builtin_amdgcn_s_setprio(1);
      #define PVSTEP(S16, G, CB) do {                                          \
        unsigned a0 = pk2bf(S16[(G)+0], S16[(G)+1]);                           \
        unsigned a1 = pk2bf(S16[(G)+2], S16[(G)+3]);                           \
        unsigned b0 = pk2bf(S16[(G)+4], S16[(G)+5]);                           \
        unsigned b1 = pk2bf(S16[(G)+6], S16[(G)+7]);                           \
        unsigned s0 = hi ? a0 : b0, s1 = hi ? a1 : b1;                         \
        unsigned r0 = __shfl_xor((int)s0, 32), r1 = __shfl_xor((int)s1, 32);   \
        union { unsigned u[4]; bf16x8 v; } pf;                                 \
        pf.u[0] = hi ? r0 : a0; pf.u[1] = hi ? r1 : a1;                        \
        pf.u[2] = hi ? b0 : r0; pf.u[3] = hi ? b1 : r1;                        \
        bf16x8 bv0 = *reinterpret_cast<const bf16x8*>((char*)sVb + swz128(l31,      (CB))); \
        bf16x8 bv1 = *reinterpret_cast<const bf16x8*>((char*)sVb + swz128(32 + l31, (CB))); \
        accO0 = __builtin_amdgcn_mfma_f32_32x32x16_bf16(pf.v, bv0, accO0, 0, 0, 0); \
        accO1 = __builtin_amdgcn_mfma_f32_32x32x16_bf16(pf.v, bv1, accO1, 0, 0, 0); \
      } while (0)
      PVSTEP(S0, 0,  0  + hi * 16);
      PVSTEP(S0, 8,  32 + hi * 16);
      PVSTEP(S1, 0,  64 + hi * 16);
      PVSTEP(S1, 8,  96 + hi * 16);
      #undef PVSTEP
      __builtin_amdgcn_s_setprio(0);
    };

    const int nt = qt * 2 + 2;    // always even
    GLOAD16(Kp + (size_t)srow[0] * HD + scol[0], &sK0[(wid * 2 + 0) * 512]);
    GLOAD16(Kp + (size_t)srow[1] * HD + scol[1], &sK0[(wid * 2 + 1) * 512]);
    GLOAD16(Vp + (size_t)srow[0] * SEQLEN + scol[0], &sV0[(wid * 2 + 0) * 512]);
    GLOAD16(Vp + (size_t)srow[1] * SEQLEN + scol[1], &sV0[(wid * 2 + 1) * 512]);
    __syncthreads();
    for (int t = 0; t < nt; t += 2) {
      {
        const int kn = (t + 1) * KVB;
        GLOAD16(Kp + (size_t)(kn + srow[0]) * HD + scol[0], &sK1[(wid * 2 + 0) * 512]);
        GLOAD16(Kp + (size_t)(kn + srow[1]) * HD + scol[1], &sK1[(wid * 2 + 1) * 512]);
        GLOAD16(Vp + (size_t)srow[0] * SEQLEN + kn + scol[0], &sV1[(wid * 2 + 0) * 512]);
        GLOAD16(Vp + (size_t)srow[1] * SEQLEN + kn + scol[1], &sV1[(wid * 2 + 1) * 512]);
      }
      compute(t * KVB, sK0, sV0);
      __syncthreads();
      if (t + 2 < nt) {
        const int kn = (t + 2) * KVB;
        GLOAD16(Kp + (size_t)(kn + srow[0]) * HD + scol[0], &sK0[(wid * 2 + 0) * 512]);
        GLOAD16(Kp + (size_t)(kn + srow[1]) * HD + scol[1], &sK0[(wid * 2 + 1) * 512]);
        GLOAD16(Vp + (size_t)srow[0] * SEQLEN + kn + scol[0], &sV0[(wid * 2 + 0) * 512]);
        GLOAD16(Vp + (size_t)srow[1] * SEQLEN + kn + scol[1], &sV0[(wid * 2 + 1) * 512]);
      }
      compute((t + 1) * KVB, sK1, sV1);
      __syncthreads();
    }
    // normalize + store: accO rows q = qrow0 + rl, cols d = dblk*32 + l31
    const float inv = 1.0f / lrun;
    #pragma unroll
    for (int reg = 0; reg < 16; reg++) {
      const int rl = (reg & 3) + 8 * (reg >> 2) + (hi << 2);
      const float invr = __shfl(inv, rl);
      const int q = qrow0 + rl;
      const size_t base = ((size_t)(b * SEQLEN + q)) * DIMSZ + h * HD;
      Og[base + l31]      = f2bf(accO0[reg] * invr);
      Og[base + 32 + l31] = f2bf(accO1[reg] * invr);
    }
  }
}

extern "C" void kernel_launch(void* const* d_in, const int* in_sizes, int n_in,
                              void* d_out, int out_size, void* d_ws, size_t ws_size,
                              hipStream_t stream)
{
  const float* x  = (const float*)d_in[0];
  const float* fc = (const float*)d_in[1];
  const float* fs = (const float*)d_in[2];
  const float* wq = (const float*)d_in[3];
  const float* wk = (const float*)d_in[4];
  const float* wv = (const float*)d_in[5];
  const float* wo = (const float*)d_in[6];
  float* out = (float*)d_out;
  char* ws = (char*)d_ws;

  unsigned short* xb    = (unsigned short*)(ws + 0);          // [4096][2048]
  unsigned short* wqkvb = (unsigned short*)(ws + 16777216);   // [3072][2048]
  unsigned short* wob   = (unsigned short*)(ws + 29360128);   // [2048][2048]
  unsigned short* Qb    = (unsigned short*)(ws + 62914560);   // [2][32][2048][64]
  unsigned short* Kb    = (unsigned short*)(ws + 79691776);   // [2][8][2048][64]
  unsigned short* Vtb   = (unsigned short*)(ws + 83886080);   // [2][8][64][2048]
  unsigned short* attnb = (unsigned short*)(ws + 88080384);   // [4096][2048]

  k_cvt_all<<<18432, 256, 0, stream>>>(x, wq, wk, wv, wo, xb, wqkvb, wob);

  dim3 g1(24, 32);   // N=3072/128, M=4096/128 — fused RoPE/Vt epilogue
  k_gemm_qkv<<<g1, 256, 0, stream>>>(xb, wqkvb, fc, fs, Qb, Kb, Vtb);

  k_attn<<<512, 256, 0, stream>>>(Qb, Kb, Vtb, attnb);

  dim3 g2(16, 32);   // N=2048/128, M=4096/128
  k_gemm_bt<0><<<g2, 256, 0, stream>>>(attnb, wob, out, NROWS, DIMSZ, DIMSZ);
}